// Round 4
// baseline (2105.377 us; speedup 1.0000x reference)
//
#include <hip/hip_runtime.h>

typedef float fv4 __attribute__((ext_vector_type(4)));
typedef __bf16 bfv8 __attribute__((ext_vector_type(8)));
typedef unsigned short u16v2 __attribute__((ext_vector_type(2)));
typedef unsigned short u16v4 __attribute__((ext_vector_type(4)));
typedef unsigned short u16v8 __attribute__((ext_vector_type(8)));

#define B_DIM 4
#define L_DIM 8192
#define D_DIM 1024
#define H_NUM 16
#define NSEG 16
#define SEG_S 512
#define MB_TOK L_DIM  // rows per batch element: 8192

__device__ __forceinline__ unsigned short f2bf(float f) {
  unsigned u = __float_as_uint(f);
  u += 0x7fffu + ((u >> 16) & 1u);  // RNE
  return (unsigned short)(u >> 16);
}
__device__ __forceinline__ float bf2f(unsigned short h) {
  return __uint_as_float((unsigned)h << 16);
}

// ---------------- fp32 -> (bf16 hi, bf16 lo) split ----------------
__global__ __launch_bounds__(256) void split_f32_bf16x2(
    const float* __restrict__ in, unsigned short* __restrict__ hi,
    unsigned short* __restrict__ lo, int n4) {
  int i = blockIdx.x * 256 + threadIdx.x;
  const int stride = gridDim.x * 256;
  for (; i < n4; i += stride) {
    fv4 v = reinterpret_cast<const fv4*>(in)[i];
    u16v4 hv, lv;
#pragma unroll
    for (int j = 0; j < 4; ++j) {
      unsigned short h = f2bf(v[j]);
      hv[j] = h;
      lv[j] = f2bf(v[j] - bf2f(h));
    }
    reinterpret_cast<u16v4*>(hi)[i] = hv;
    reinterpret_cast<u16v4*>(lo)[i] = lv;
  }
}

// ---------------- C[M,N] = A @ B^T, split-bf16 3-product MFMA ----------------
// Output: if Chi != nullptr, write split-bf16 (hi,lo); else fp32 C (+bias).
#define GT_PAD 40
__global__ __launch_bounds__(256) void gemm_bt_split(
    const __bf16* __restrict__ Ah, const __bf16* __restrict__ Al,
    const __bf16* __restrict__ Bh, const __bf16* __restrict__ Bl,
    float* __restrict__ C, const float* __restrict__ bias,
    unsigned short* __restrict__ Chi, unsigned short* __restrict__ Clo,
    int M, int N, int K) {
  __shared__ __bf16 sAh[128 * GT_PAD], sAl[128 * GT_PAD];
  __shared__ __bf16 sBh[128 * GT_PAD], sBl[128 * GT_PAD];
  const int tid = threadIdx.x;
  const int lane = tid & 63;
  const int wid = tid >> 6;
  const int wr = wid >> 1, wc = wid & 1;
  const int mBase = blockIdx.y * 128;
  const int nBase = blockIdx.x * 128;

  fv4 acc[4][4] = {};

  const int arowRd = wr * 64 + (lane & 15);
  const int browRd = wc * 64 + (lane & 15);
  const int koff = (lane >> 4) << 3;

  for (int k0 = 0; k0 < K; k0 += 32) {
    __syncthreads();
#pragma unroll
    for (int it = 0; it < 2; ++it) {
      const int idx = it * 256 + tid;
      const int row = idx >> 2, ch = idx & 3;
      const int ldo = row * GT_PAD + ch * 8;
      const long ga = (long)(mBase + row) * K + k0 + ch * 8;
      const long gb = (long)(nBase + row) * K + k0 + ch * 8;
      *(bfv8*)&sAh[ldo] = *(const bfv8*)&Ah[ga];
      *(bfv8*)&sAl[ldo] = *(const bfv8*)&Al[ga];
      *(bfv8*)&sBh[ldo] = *(const bfv8*)&Bh[gb];
      *(bfv8*)&sBl[ldo] = *(const bfv8*)&Bl[gb];
    }
    __syncthreads();
    bfv8 fah[4], fal[4], fbh[4], fbl[4];
#pragma unroll
    for (int i = 0; i < 4; ++i) {
      fah[i] = *(const bfv8*)&sAh[(arowRd + i * 16) * GT_PAD + koff];
      fal[i] = *(const bfv8*)&sAl[(arowRd + i * 16) * GT_PAD + koff];
      fbh[i] = *(const bfv8*)&sBh[(browRd + i * 16) * GT_PAD + koff];
      fbl[i] = *(const bfv8*)&sBl[(browRd + i * 16) * GT_PAD + koff];
    }
#pragma unroll
    for (int i = 0; i < 4; ++i)
#pragma unroll
      for (int j = 0; j < 4; ++j) {
        acc[i][j] = __builtin_amdgcn_mfma_f32_16x16x32_bf16(fah[i], fbh[j], acc[i][j], 0, 0, 0);
        acc[i][j] = __builtin_amdgcn_mfma_f32_16x16x32_bf16(fah[i], fbl[j], acc[i][j], 0, 0, 0);
        acc[i][j] = __builtin_amdgcn_mfma_f32_16x16x32_bf16(fal[i], fbh[j], acc[i][j], 0, 0, 0);
      }
  }

  // C/D layout (verified m89): col = lane&15, row = 4*(lane>>4) + reg
  const int crow0 = mBase + wr * 64 + ((lane >> 4) << 2);
  const int ccol0 = nBase + wc * 64 + (lane & 15);
  if (Chi) {
#pragma unroll
    for (int j = 0; j < 4; ++j) {
      const int col = ccol0 + j * 16;
#pragma unroll
      for (int i = 0; i < 4; ++i) {
        const long rb = (long)(crow0 + i * 16) * N + col;
#pragma unroll
        for (int r = 0; r < 4; ++r) {
          const float v = acc[i][j][r];
          const unsigned short hb = f2bf(v);
          Chi[rb + (long)r * N] = hb;
          Clo[rb + (long)r * N] = f2bf(v - bf2f(hb));
        }
      }
    }
  } else {
#pragma unroll
    for (int j = 0; j < 4; ++j) {
      const int col = ccol0 + j * 16;
      const float bv = bias ? bias[col] : 0.f;
#pragma unroll
      for (int i = 0; i < 4; ++i) {
        const long rb = (long)(crow0 + i * 16) * N + col;
#pragma unroll
        for (int r = 0; r < 4; ++r)
          C[rb + (long)r * N] = acc[i][j][r] + bv;
      }
    }
  }
}

// ---------------- per-(seg,h) outer products (split-bf16 K/V inputs) ----------------
__global__ __launch_bounds__(256) void seg_outer(
    const unsigned short* __restrict__ Kh, const unsigned short* __restrict__ Kl,
    const unsigned short* __restrict__ Vh, const unsigned short* __restrict__ Vl,
    float* __restrict__ U, float* __restrict__ Zs) {
  const int shd = blockIdx.x;
  const int seg = shd >> 4, h = shd & 15;
  const int tid = threadIdx.x;
  const int dgrp = tid >> 6, e = tid & 63;
  __shared__ float sAK[16 * 64], sVv[16 * 64];
  const long base = ((long)seg * SEG_S) * D_DIM + h * 64;
  float acc[16] = {};
  float zacc = 0.f;
  for (int s0 = 0; s0 < SEG_S; s0 += 16) {
    __syncthreads();
#pragma unroll
    for (int r = 0; r < 4; ++r) {
      const int idx = r * 256 + tid;
      const int sl = idx >> 6, d = idx & 63;
      const long gg = base + (long)(s0 + sl) * D_DIM + d;
      const float kv = bf2f(Kh[gg]) + bf2f(Kl[gg]);
      sAK[idx] = kv > 0.f ? kv + 1.f : __expf(kv);
      sVv[idx] = bf2f(Vh[gg]) + bf2f(Vl[gg]);
    }
    __syncthreads();
#pragma unroll
    for (int sl = 0; sl < 16; ++sl) {
      const float vv = sVv[sl * 64 + e];
#pragma unroll
      for (int i = 0; i < 16; ++i)
        acc[i] += sAK[sl * 64 + dgrp * 16 + i] * vv;
    }
    if (tid < 64) {
#pragma unroll
      for (int sl = 0; sl < 16; ++sl) zacc += sAK[sl * 64 + tid];
    }
  }
  const long ub = (long)shd * 4096;
#pragma unroll
  for (int i = 0; i < 16; ++i)
    U[ub + (dgrp * 16 + i) * 64 + e] = acc[i];
  if (tid < 64) Zs[(long)shd * 64 + tid] = zacc;
}

// ---------------- exclusive prefix over segments ----------------
__global__ __launch_bounds__(256) void seg_prefix(
    const float* __restrict__ U, const float* __restrict__ Zs,
    float* __restrict__ Mem, float* __restrict__ Zp) {
  const int h = blockIdx.x;
  const int tid = threadIdx.x;
  for (int j = tid; j < 4096; j += 256) {
    float run = 0.f;
#pragma unroll
    for (int t = 0; t < NSEG; ++t) {
      const long idx = ((long)(t * 16 + h)) * 4096 + j;
      Mem[idx] = run;
      run += U[idx];
    }
  }
  if (tid < 64) {
    float run = 0.f;
#pragma unroll
    for (int t = 0; t < NSEG; ++t) {
      const long idx = ((long)(t * 16 + h)) * 64 + tid;
      Zp[idx] = run;
      run += Zs[idx];
    }
  }
}

// ---------------- MFMA segment attention, 4 query-tiles per block ----------------
// block = 256 thr (4 waves); block covers 256 queries of one (seg,h).
// All Q/K/V inputs pre-split (hi,lo) bf16 — staging is pure copies.
__global__ __launch_bounds__(256, 2) void attn_seg_mfma(
    const unsigned short* __restrict__ Qh, const unsigned short* __restrict__ Ql,
    const unsigned short* __restrict__ Kh, const unsigned short* __restrict__ Kl,
    const unsigned short* __restrict__ Vh, const unsigned short* __restrict__ Vl,
    const int* __restrict__ mask,
    const float* __restrict__ Mem, const float* __restrict__ Zp,
    const float* __restrict__ betas,
    unsigned short* __restrict__ Oh, unsigned short* __restrict__ Ol) {
  __shared__ __bf16 sKh[64 * 72], sKl[64 * 72];       // K [key][d] (later Mem^T [e][d])
  __shared__ __bf16 sVTh[64 * 72], sVTl[64 * 72];     // V^T [e][key]
  __shared__ __bf16 sPh[4][16 * 72], sPl[4][16 * 72]; // per-wave P [q][key]
  __shared__ float sMaskF[64], sZ[64], sGate[64];

  const int bx = blockIdx.x;
  const int qgrp = bx & 1, h = (bx >> 1) & 15, seg = bx >> 5;
  const int sh = seg * 16 + h;
  const int tid = threadIdx.x;
  const int lane = tid & 63, w = tid >> 6;
  const int g = lane >> 4, ln16 = lane & 15;

  // ---- Q fragments for 4 tiles, direct split loads ----
  bfv8 qh[4][2], ql[4][2];
#pragma unroll
  for (int t = 0; t < 4; ++t) {
    const long qb = (long)(seg * SEG_S + qgrp * 256 + t * 64 + w * 16 + ln16) * D_DIM + h * 64;
#pragma unroll
    for (int dt = 0; dt < 2; ++dt) {
      qh[t][dt] = *(const bfv8*)&Qh[qb + dt * 32 + g * 8];
      ql[t][dt] = *(const bfv8*)&Ql[qb + dt * 32 + g * 8];
    }
  }

  fv4 O[4][4] = {};
  float m_run[4], l_run[4];
#pragma unroll
  for (int t = 0; t < 4; ++t) { m_run[t] = -1e30f; l_run[t] = 0.f; }
  const long kvbase0 = (long)(seg * SEG_S) * D_DIM + h * 64;

  for (int c = 0; c < 8; ++c) {
    __syncthreads();
    // ---- stage K chunk [64 keys][64 d]: pure u16v8 copies ----
    {
      const int row = tid >> 2, d0 = (tid & 3) * 16;
      const long ga = kvbase0 + (long)(c * 64 + row) * D_DIM + d0;
      *(u16v8*)&sKh[row * 72 + d0]     = *(const u16v8*)&Kh[ga];
      *(u16v8*)&sKh[row * 72 + d0 + 8] = *(const u16v8*)&Kh[ga + 8];
      *(u16v8*)&sKl[row * 72 + d0]     = *(const u16v8*)&Kl[ga];
      *(u16v8*)&sKl[row * 72 + d0 + 8] = *(const u16v8*)&Kl[ga + 8];
    }
    // ---- stage V^T chunk [64 e][64 keys]: quad-pack transpose, no conversion ----
    {
      const int e4 = (tid & 15) * 4, p4 = (tid >> 4) * 4;
      u16v4 vvh[4], vvl[4];
#pragma unroll
      for (int i = 0; i < 4; ++i) {
        const long ga = kvbase0 + (long)(c * 64 + p4 + i) * D_DIM + e4;
        vvh[i] = *(const u16v4*)&Vh[ga];
        vvl[i] = *(const u16v4*)&Vl[ga];
      }
#pragma unroll
      for (int je = 0; je < 4; ++je) {
        u16v4 hv, lv;
#pragma unroll
        for (int i = 0; i < 4; ++i) { hv[i] = vvh[i][je]; lv[i] = vvl[i][je]; }
        *(u16v4*)&sVTh[(e4 + je) * 72 + p4] = hv;
        *(u16v4*)&sVTl[(e4 + je) * 72 + p4] = lv;
      }
    }
    if (tid < 64) sMaskF[tid] = (mask[seg * SEG_S + c * 64 + tid] == 0) ? 1.f : 0.f;
    __syncthreads();

#pragma unroll
    for (int t = 0; t < 4; ++t) {
      // ---- S^T = K . Q^T (split 3-product) ----
      fv4 sc[4];
#pragma unroll
      for (int kt = 0; kt < 4; ++kt) {
        const int ro = (kt * 16 + ln16) * 72 + g * 8;
        bfv8 kh0 = *(const bfv8*)&sKh[ro], kh1 = *(const bfv8*)&sKh[ro + 32];
        bfv8 kl0 = *(const bfv8*)&sKl[ro], kl1 = *(const bfv8*)&sKl[ro + 32];
        fv4 s = {};
        s = __builtin_amdgcn_mfma_f32_16x16x32_bf16(kh0, qh[t][0], s, 0, 0, 0);
        s = __builtin_amdgcn_mfma_f32_16x16x32_bf16(kh1, qh[t][1], s, 0, 0, 0);
        s = __builtin_amdgcn_mfma_f32_16x16x32_bf16(kh0, ql[t][0], s, 0, 0, 0);
        s = __builtin_amdgcn_mfma_f32_16x16x32_bf16(kh1, ql[t][1], s, 0, 0, 0);
        s = __builtin_amdgcn_mfma_f32_16x16x32_bf16(kl0, qh[t][0], s, 0, 0, 0);
        s = __builtin_amdgcn_mfma_f32_16x16x32_bf16(kl1, qh[t][1], s, 0, 0, 0);
        sc[kt] = s;
      }
      // ---- online softmax ----
      float pmax = -3.0e38f;
#pragma unroll
      for (int kt = 0; kt < 4; ++kt)
#pragma unroll
        for (int r = 0; r < 4; ++r) {
          float v = sc[kt][r] * 0.125f;
          if (sMaskF[kt * 16 + g * 4 + r] != 0.f) v = -1e9f;
          sc[kt][r] = v;
          pmax = fmaxf(pmax, v);
        }
      pmax = fmaxf(pmax, __shfl_xor(pmax, 16));
      pmax = fmaxf(pmax, __shfl_xor(pmax, 32));
      const float m_new = fmaxf(m_run[t], pmax);
      const float resc = __expf(m_run[t] - m_new);
      float psum = 0.f;
#pragma unroll
      for (int kt = 0; kt < 4; ++kt)
#pragma unroll
        for (int r = 0; r < 4; ++r) {
          const float p = __expf(sc[kt][r] - m_new);
          sc[kt][r] = p;
          psum += p;
        }
      psum += __shfl_xor(psum, 16);
      psum += __shfl_xor(psum, 32);
      l_run[t] = l_run[t] * resc + psum;
      m_run[t] = m_new;
#pragma unroll
      for (int et = 0; et < 4; ++et)
#pragma unroll
        for (int r = 0; r < 4; ++r) O[t][et][r] *= resc;

      // ---- P -> per-wave LDS [q][key] split-bf16 ----
#pragma unroll
      for (int kt = 0; kt < 4; ++kt)
#pragma unroll
        for (int r2 = 0; r2 < 2; ++r2) {
          u16v2 hv, lv;
#pragma unroll
          for (int j = 0; j < 2; ++j) {
            const float p = sc[kt][r2 * 2 + j];
            unsigned short h0 = f2bf(p);
            hv[j] = h0; lv[j] = f2bf(p - bf2f(h0));
          }
          const int off = ln16 * 72 + kt * 16 + g * 4 + r2 * 2;
          *(u16v2*)&sPh[w][off] = hv;
          *(u16v2*)&sPl[w][off] = lv;
        }
      bfv8 pfh[2], pfl[2];
#pragma unroll
      for (int kt2 = 0; kt2 < 2; ++kt2) {
        pfh[kt2] = *(const bfv8*)&sPh[w][ln16 * 72 + kt2 * 32 + g * 8];
        pfl[kt2] = *(const bfv8*)&sPl[w][ln16 * 72 + kt2 * 32 + g * 8];
      }
      // ---- O^T += V^T . P ----
#pragma unroll
      for (int et = 0; et < 4; ++et) {
        const int ro = (et * 16 + ln16) * 72 + g * 8;
        bfv8 vh0 = *(const bfv8*)&sVTh[ro], vh1 = *(const bfv8*)&sVTh[ro + 32];
        bfv8 vl0 = *(const bfv8*)&sVTl[ro], vl1 = *(const bfv8*)&sVTl[ro + 32];
        fv4 o = O[t][et];
        o = __builtin_amdgcn_mfma_f32_16x16x32_bf16(vh0, pfh[0], o, 0, 0, 0);
        o = __builtin_amdgcn_mfma_f32_16x16x32_bf16(vh1, pfh[1], o, 0, 0, 0);
        o = __builtin_amdgcn_mfma_f32_16x16x32_bf16(vh0, pfl[0], o, 0, 0, 0);
        o = __builtin_amdgcn_mfma_f32_16x16x32_bf16(vh1, pfl[1], o, 0, 0, 0);
        o = __builtin_amdgcn_mfma_f32_16x16x32_bf16(vl0, pfh[0], o, 0, 0, 0);
        o = __builtin_amdgcn_mfma_f32_16x16x32_bf16(vl1, pfh[1], o, 0, 0, 0);
        O[t][et] = o;
      }
    }
  }

  // ---- memory-read term ----
  __syncthreads();
  {  // stage Mem^T [e][d] into sKh/sKl (fp32 source, f2bf once per block)
    const int e4 = (tid & 15) * 4, p4 = (tid >> 4) * 4;
    const float* Memp = Mem + (long)sh * 4096;
    fv4 mv[4];
#pragma unroll
    for (int i = 0; i < 4; ++i) mv[i] = *(const fv4*)&Memp[(p4 + i) * 64 + e4];
#pragma unroll
    for (int je = 0; je < 4; ++je) {
      u16v4 hv, lv;
#pragma unroll
      for (int i = 0; i < 4; ++i) {
        unsigned short h0 = f2bf(mv[i][je]);
        hv[i] = h0; lv[i] = f2bf(mv[i][je] - bf2f(h0));
      }
      *(u16v4*)&sKh[(e4 + je) * 72 + p4] = hv;
      *(u16v4*)&sKl[(e4 + je) * 72 + p4] = lv;
    }
  }
  if (tid < 64) {
    sZ[tid] = Zp[(long)sh * 64 + tid];
    sGate[tid] = 1.f / (1.f + __expf(-betas[h * 64 + tid]));
  }
  __syncthreads();

#pragma unroll
  for (int t = 0; t < 4; ++t) {
    // aq = elu(q)+1 in-register; denom = aq . z
    float dpart = 0.f;
#pragma unroll
    for (int dt = 0; dt < 2; ++dt) {
      bfv8 ah, al;
#pragma unroll
      for (int j = 0; j < 8; ++j) {
        const float x = (float)qh[t][dt][j] + (float)ql[t][dt][j];
        const float a = x > 0.f ? x + 1.f : __expf(x);
        dpart += a * sZ[dt * 32 + g * 8 + j];
        unsigned short h0 = f2bf(a);
        ah[j] = __builtin_bit_cast(__bf16, h0);
        al[j] = __builtin_bit_cast(__bf16, f2bf(a - bf2f(h0)));
      }
      qh[t][dt] = ah;
      ql[t][dt] = al;
    }
    dpart += __shfl_xor(dpart, 16);
    dpart += __shfl_xor(dpart, 32);
    const float invden = 1.f / (dpart + 1e-9f);
    const float invl = 1.f / l_run[t];

    const long obase = (long)(seg * SEG_S + qgrp * 256 + t * 64 + w * 16 + ln16) * D_DIM + h * 64;
#pragma unroll
    for (int et = 0; et < 4; ++et) {
      const int ro = (et * 16 + ln16) * 72 + g * 8;
      bfv8 mh0 = *(const bfv8*)&sKh[ro], mh1 = *(const bfv8*)&sKh[ro + 32];
      bfv8 ml0 = *(const bfv8*)&sKl[ro], ml1 = *(const bfv8*)&sKl[ro + 32];
      fv4 o = {};
      o = __builtin_amdgcn_mfma_f32_16x16x32_bf16(mh0, qh[t][0], o, 0, 0, 0);
      o = __builtin_amdgcn_mfma_f32_16x16x32_bf16(mh1, qh[t][1], o, 0, 0, 0);
      o = __builtin_amdgcn_mfma_f32_16x16x32_bf16(mh0, ql[t][0], o, 0, 0, 0);
      o = __builtin_amdgcn_mfma_f32_16x16x32_bf16(mh1, ql[t][1], o, 0, 0, 0);
      o = __builtin_amdgcn_mfma_f32_16x16x32_bf16(ml0, qh[t][0], o, 0, 0, 0);
      o = __builtin_amdgcn_mfma_f32_16x16x32_bf16(ml1, qh[t][1], o, 0, 0, 0);
      // gate combine + split-bf16 store
      u16v4 hv, lv;
#pragma unroll
      for (int r = 0; r < 4; ++r) {
        const int e = et * 16 + g * 4 + r;
        const float gt = sGate[e];
        const float att = gt * o[r] * invden + (1.f - gt) * O[t][et][r] * invl;
        unsigned short h0 = f2bf(att);
        hv[r] = h0;
        lv[r] = f2bf(att - bf2f(h0));
      }
      *(u16v4*)&Oh[obase + et * 16 + g * 4] = hv;
      *(u16v4*)&Ol[obase + et * 16 + g * 4] = lv;
    }
  }
}

// ---------------- host launch: batch-tiled to bound workspace ----------------
extern "C" void kernel_launch(void* const* d_in, const int* in_sizes, int n_in,
                              void* d_out, int out_size, void* d_ws, size_t ws_size,
                              hipStream_t stream) {
  (void)in_sizes; (void)n_in; (void)out_size;
  const float* x     = (const float*)d_in[0];
  const int*   mask  = (const int*)d_in[1];
  const float* wq    = (const float*)d_in[2];
  const float* wk    = (const float*)d_in[3];
  const float* wv    = (const float*)d_in[4];
  const float* wo    = (const float*)d_in[5];
  const float* wob   = (const float*)d_in[6];
  const float* betas = (const float*)d_in[7];
  float* out = (float*)d_out;

  const size_t TOKB = (size_t)MB_TOK * D_DIM;
  char* ws = (char*)d_ws;
  size_t off = 0;
  auto alloc = [&](size_t bytes) {
    char* p = ws + off;
    off += (bytes + 255) & ~(size_t)255;
    return p;
  };
  unsigned short* wsp[8];
  for (int i = 0; i < 8; ++i)
    wsp[i] = (unsigned short*)alloc((size_t)D_DIM * D_DIM * 2);
  unsigned short* xh = (unsigned short*)alloc(TOKB * 2);
  unsigned short* xl = (unsigned short*)alloc(TOKB * 2);
  unsigned short* qh_ = (unsigned short*)alloc(TOKB * 2);
  unsigned short* ql_ = (unsigned short*)alloc(TOKB * 2);
  unsigned short* kh_ = (unsigned short*)alloc(TOKB * 2);
  unsigned short* kl_ = (unsigned short*)alloc(TOKB * 2);
  unsigned short* vh_ = (unsigned short*)alloc(TOKB * 2);
  unsigned short* vl_ = (unsigned short*)alloc(TOKB * 2);
  float* U   = (float*)alloc((size_t)NSEG * H_NUM * 4096 * 4);
  float* Mem = (float*)alloc((size_t)NSEG * H_NUM * 4096 * 4);
  float* Zs  = (float*)alloc((size_t)NSEG * H_NUM * 64 * 4);
  float* Zp  = (float*)alloc((size_t)NSEG * H_NUM * 64 * 4);
  unsigned short* atth = xh;  // x dead after QKV GEMMs
  unsigned short* attl = xl;

  if (off > ws_size) return;

  const float* wsrc[4] = {wq, wk, wv, wo};
  for (int i = 0; i < 4; ++i)
    split_f32_bf16x2<<<1024, 256, 0, stream>>>(wsrc[i], wsp[2 * i], wsp[2 * i + 1],
                                               D_DIM * D_DIM / 4);

  dim3 ggrid(D_DIM / 128, MB_TOK / 128);
  for (int b = 0; b < B_DIM; ++b) {
    const float* xb = x + (size_t)b * TOKB;
    const int* maskb = mask + (size_t)b * L_DIM;
    float* outb = out + (size_t)b * TOKB;

    split_f32_bf16x2<<<2048, 256, 0, stream>>>(xb, xh, xl, (int)(TOKB / 4));

    gemm_bt_split<<<ggrid, 256, 0, stream>>>(
        (const __bf16*)xh, (const __bf16*)xl, (const __bf16*)wsp[0], (const __bf16*)wsp[1],
        nullptr, nullptr, qh_, ql_, MB_TOK, D_DIM, D_DIM);
    gemm_bt_split<<<ggrid, 256, 0, stream>>>(
        (const __bf16*)xh, (const __bf16*)xl, (const __bf16*)wsp[2], (const __bf16*)wsp[3],
        nullptr, nullptr, kh_, kl_, MB_TOK, D_DIM, D_DIM);
    gemm_bt_split<<<ggrid, 256, 0, stream>>>(
        (const __bf16*)xh, (const __bf16*)xl, (const __bf16*)wsp[4], (const __bf16*)wsp[5],
        nullptr, nullptr, vh_, vl_, MB_TOK, D_DIM, D_DIM);

    seg_outer<<<NSEG * H_NUM, 256, 0, stream>>>(kh_, kl_, vh_, vl_, U, Zs);
    seg_prefix<<<H_NUM, 256, 0, stream>>>(U, Zs, Mem, Zp);

    attn_seg_mfma<<<NSEG * H_NUM * 2, 256, 0, stream>>>(
        qh_, ql_, kh_, kl_, vh_, vl_, maskb, Mem, Zp, betas, atth, attl);

    gemm_bt_split<<<ggrid, 256, 0, stream>>>(
        (const __bf16*)atth, (const __bf16*)attl, (const __bf16*)wsp[6], (const __bf16*)wsp[7],
        out ? outb : nullptr, wob, nullptr, nullptr, MB_TOK, D_DIM, D_DIM);
  }
}

// Round 5
// 1571.979 us; speedup vs baseline: 1.3393x; 1.3393x over previous
//
#include <hip/hip_runtime.h>

typedef float fv2 __attribute__((ext_vector_type(2)));
typedef float fv4 __attribute__((ext_vector_type(4)));
typedef __bf16 bfv8 __attribute__((ext_vector_type(8)));
typedef unsigned short u16v4 __attribute__((ext_vector_type(4)));
typedef unsigned int u32v2 __attribute__((ext_vector_type(2)));
typedef unsigned int u32v4 __attribute__((ext_vector_type(4)));

#define B_DIM 4
#define L_DIM 8192
#define D_DIM 1024
#define H_NUM 16
#define NSEG 16
#define SEG_S 512
#define MB_TOK L_DIM  // rows per batch element: 8192

__device__ __forceinline__ unsigned short f2bf(float f) {
  unsigned u = __float_as_uint(f);
  u += 0x7fffu + ((u >> 16) & 1u);  // RNE
  return (unsigned short)(u >> 16);
}
__device__ __forceinline__ float bf2f(unsigned short h) {
  return __uint_as_float((unsigned)h << 16);
}
__device__ __forceinline__ unsigned packbf2(float v) {
  unsigned short hb = f2bf(v);
  unsigned short lb = f2bf(v - bf2f(hb));
  return (unsigned)hb | ((unsigned)lb << 16);
}
__device__ __forceinline__ float up_hi(unsigned u) { return __uint_as_float(u << 16); }
__device__ __forceinline__ float up_lo(unsigned u) { return __uint_as_float(u & 0xffff0000u); }

// unpack 8 packed elements (2 x u32v4) -> u32v4 of 8 hi-bf16 and 8 lo-bf16
__device__ __forceinline__ void unpack8(u32v4 a, u32v4 b, u32v4& hi, u32v4& lo) {
  hi[0] = __builtin_amdgcn_perm(a[1], a[0], 0x05040100u);
  hi[1] = __builtin_amdgcn_perm(a[3], a[2], 0x05040100u);
  hi[2] = __builtin_amdgcn_perm(b[1], b[0], 0x05040100u);
  hi[3] = __builtin_amdgcn_perm(b[3], b[2], 0x05040100u);
  lo[0] = __builtin_amdgcn_perm(a[1], a[0], 0x07060302u);
  lo[1] = __builtin_amdgcn_perm(a[3], a[2], 0x07060302u);
  lo[2] = __builtin_amdgcn_perm(b[1], b[0], 0x07060302u);
  lo[3] = __builtin_amdgcn_perm(b[3], b[2], 0x07060302u);
}

// ---------------- fp32 -> packed (hi|lo<<16) split ----------------
__global__ __launch_bounds__(256) void split_pack(
    const float* __restrict__ in, unsigned* __restrict__ outp, int n4) {
  int i = blockIdx.x * 256 + threadIdx.x;
  const int stride = gridDim.x * 256;
  for (; i < n4; i += stride) {
    fv4 v = reinterpret_cast<const fv4*>(in)[i];
    u32v4 p;
#pragma unroll
    for (int j = 0; j < 4; ++j) p[j] = packbf2(v[j]);
    reinterpret_cast<u32v4*>(outp)[i] = p;
  }
}

// ---------------- C[M,N] = A @ B^T, split-bf16 3-product MFMA, packed I/O ----------------
#define GT_PAD 40
__global__ __launch_bounds__(256) void gemm_bt_packed(
    const unsigned* __restrict__ Ap, const unsigned* __restrict__ Bp,
    float* __restrict__ C, const float* __restrict__ bias,
    unsigned* __restrict__ Cp, int M, int N, int K) {
  __shared__ __bf16 sAh[128 * GT_PAD], sAl[128 * GT_PAD];
  __shared__ __bf16 sBh[128 * GT_PAD], sBl[128 * GT_PAD];
  const int tid = threadIdx.x;
  const int lane = tid & 63;
  const int wid = tid >> 6;
  const int wr = wid >> 1, wc = wid & 1;
  const int mBase = blockIdx.y * 128;
  const int nBase = blockIdx.x * 128;

  fv4 acc[4][4] = {};

  const int arowRd = wr * 64 + (lane & 15);
  const int browRd = wc * 64 + (lane & 15);
  const int koff = (lane >> 4) << 3;

  for (int k0 = 0; k0 < K; k0 += 32) {
    __syncthreads();
#pragma unroll
    for (int it = 0; it < 2; ++it) {
      const int idx = it * 256 + tid;
      const int row = idx >> 2, ch = idx & 3;
      const int ldo = row * GT_PAD + ch * 8;
      const long ga = (long)(mBase + row) * K + k0 + ch * 8;
      const long gb = (long)(nBase + row) * K + k0 + ch * 8;
      u32v4 a0 = *(const u32v4*)&Ap[ga], a1 = *(const u32v4*)&Ap[ga + 4];
      u32v4 b0 = *(const u32v4*)&Bp[gb], b1 = *(const u32v4*)&Bp[gb + 4];
      u32v4 hi, lo;
      unpack8(a0, a1, hi, lo);
      *(u32v4*)&sAh[ldo] = hi;
      *(u32v4*)&sAl[ldo] = lo;
      unpack8(b0, b1, hi, lo);
      *(u32v4*)&sBh[ldo] = hi;
      *(u32v4*)&sBl[ldo] = lo;
    }
    __syncthreads();
    bfv8 fah[4], fal[4], fbh[4], fbl[4];
#pragma unroll
    for (int i = 0; i < 4; ++i) {
      fah[i] = *(const bfv8*)&sAh[(arowRd + i * 16) * GT_PAD + koff];
      fal[i] = *(const bfv8*)&sAl[(arowRd + i * 16) * GT_PAD + koff];
      fbh[i] = *(const bfv8*)&sBh[(browRd + i * 16) * GT_PAD + koff];
      fbl[i] = *(const bfv8*)&sBl[(browRd + i * 16) * GT_PAD + koff];
    }
#pragma unroll
    for (int i = 0; i < 4; ++i)
#pragma unroll
      for (int j = 0; j < 4; ++j) {
        acc[i][j] = __builtin_amdgcn_mfma_f32_16x16x32_bf16(fah[i], fbh[j], acc[i][j], 0, 0, 0);
        acc[i][j] = __builtin_amdgcn_mfma_f32_16x16x32_bf16(fah[i], fbl[j], acc[i][j], 0, 0, 0);
        acc[i][j] = __builtin_amdgcn_mfma_f32_16x16x32_bf16(fal[i], fbh[j], acc[i][j], 0, 0, 0);
      }
  }

  // C/D layout (verified m89): col = lane&15, row = 4*(lane>>4) + reg
  const int crow0 = mBase + wr * 64 + ((lane >> 4) << 2);
  const int ccol0 = nBase + wc * 64 + (lane & 15);
  if (Cp) {
#pragma unroll
    for (int j = 0; j < 4; ++j) {
      const int col = ccol0 + j * 16;
#pragma unroll
      for (int i = 0; i < 4; ++i) {
        const long rb = (long)(crow0 + i * 16) * N + col;
#pragma unroll
        for (int r = 0; r < 4; ++r)
          Cp[rb + (long)r * N] = packbf2(acc[i][j][r]);
      }
    }
  } else {
#pragma unroll
    for (int j = 0; j < 4; ++j) {
      const int col = ccol0 + j * 16;
      const float bv = bias ? bias[col] : 0.f;
#pragma unroll
      for (int i = 0; i < 4; ++i) {
        const long rb = (long)(crow0 + i * 16) * N + col;
#pragma unroll
        for (int r = 0; r < 4; ++r)
          C[rb + (long)r * N] = acc[i][j][r] + bv;
      }
    }
  }
}

// ---------------- per-(seg,h) outer products (packed K/V inputs) ----------------
__global__ __launch_bounds__(256) void seg_outer(
    const unsigned* __restrict__ Kp, const unsigned* __restrict__ Vp,
    float* __restrict__ U, float* __restrict__ Zs) {
  const int shd = blockIdx.x;
  const int seg = shd >> 4, h = shd & 15;
  const int tid = threadIdx.x;
  const int dgrp = tid >> 6, e = tid & 63;
  __shared__ float sAK[16 * 64], sVv[16 * 64];
  const long base = ((long)seg * SEG_S) * D_DIM + h * 64;
  float acc[16] = {};
  float zacc = 0.f;
  for (int s0 = 0; s0 < SEG_S; s0 += 16) {
    __syncthreads();
#pragma unroll
    for (int r = 0; r < 4; ++r) {
      const int idx = r * 256 + tid;
      const int sl = idx >> 6, d = idx & 63;
      const long gg = base + (long)(s0 + sl) * D_DIM + d;
      const unsigned ku = Kp[gg];
      const float kv = up_hi(ku) + up_lo(ku);
      sAK[idx] = kv > 0.f ? kv + 1.f : __expf(kv);
      const unsigned vu = Vp[gg];
      sVv[idx] = up_hi(vu) + up_lo(vu);
    }
    __syncthreads();
#pragma unroll
    for (int sl = 0; sl < 16; ++sl) {
      const float vv = sVv[sl * 64 + e];
#pragma unroll
      for (int i = 0; i < 16; ++i)
        acc[i] += sAK[sl * 64 + dgrp * 16 + i] * vv;
    }
    if (tid < 64) {
#pragma unroll
      for (int sl = 0; sl < 16; ++sl) zacc += sAK[sl * 64 + tid];
    }
  }
  const long ub = (long)shd * 4096;
#pragma unroll
  for (int i = 0; i < 16; ++i)
    U[ub + (dgrp * 16 + i) * 64 + e] = acc[i];
  if (tid < 64) Zs[(long)shd * 64 + tid] = zacc;
}

// ---------------- exclusive prefix over segments ----------------
__global__ __launch_bounds__(256) void seg_prefix(
    const float* __restrict__ U, const float* __restrict__ Zs,
    float* __restrict__ Mem, float* __restrict__ Zp) {
  const int h = blockIdx.x;
  const int tid = threadIdx.x;
  for (int j = tid; j < 4096; j += 256) {
    float run = 0.f;
#pragma unroll
    for (int t = 0; t < NSEG; ++t) {
      const long idx = ((long)(t * 16 + h)) * 4096 + j;
      Mem[idx] = run;
      run += U[idx];
    }
  }
  if (tid < 64) {
    float run = 0.f;
#pragma unroll
    for (int t = 0; t < NSEG; ++t) {
      const long idx = ((long)(t * 16 + h)) * 64 + tid;
      Zp[idx] = run;
      run += Zs[idx];
    }
  }
}

// ---------------- MFMA segment attention: 512 thr, 8 waves, 16 q/wave ----------------
__global__ __launch_bounds__(512, 4) void attn_seg_mfma(
    const unsigned* __restrict__ Qp, const unsigned* __restrict__ Kp,
    const unsigned* __restrict__ Vp, const int* __restrict__ mask,
    const float* __restrict__ Mem, const float* __restrict__ Zp,
    const float* __restrict__ betas, unsigned* __restrict__ Op) {
  __shared__ __bf16 sKh[64 * 72], sKl[64 * 72];    // K chunk [key][d]; later Mem^T [e][d]
  __shared__ __bf16 sVTh[64 * 72], sVTl[64 * 72];  // V^T [e][key]
  __shared__ __bf16 sP[8][16 * 72];                // per-wave P (single bf16) [q][key]
  __shared__ float sMadd[64], sZ[64], sGate[64];

  const int bx = blockIdx.x;
  const int qblk = bx & 3, h = (bx >> 2) & 15, seg = bx >> 6;
  const int sh = seg * 16 + h;
  const int tid = threadIdx.x;
  const int lane = tid & 63, w = tid >> 6;
  const int g = lane >> 4, ln16 = lane & 15;

  // ---- Q fragments (16 queries per wave), packed loads ----
  const int qglob = seg * SEG_S + qblk * 128 + w * 16 + ln16;
  const long qbase = (long)qglob * D_DIM + h * 64;
  bfv8 qh[2], ql[2];
#pragma unroll
  for (int dt = 0; dt < 2; ++dt) {
    u32v4 a = *(const u32v4*)&Qp[qbase + dt * 32 + g * 8];
    u32v4 b = *(const u32v4*)&Qp[qbase + dt * 32 + g * 8 + 4];
    u32v4 hi, lo;
    unpack8(a, b, hi, lo);
    qh[dt] = __builtin_bit_cast(bfv8, hi);
    ql[dt] = __builtin_bit_cast(bfv8, lo);
  }

  fv4 O[4] = {};
  float m_run = -1e30f, l_run = 0.f;
  const long kvbase0 = (long)(seg * SEG_S) * D_DIM + h * 64;

  for (int c = 0; c < 8; ++c) {
    __syncthreads();
    // ---- stage K [64 key][64 d]: 512 thr, 8 els each ----
    {
      const int row = tid >> 3, d0 = (tid & 7) * 8;
      const long ga = kvbase0 + (long)(c * 64 + row) * D_DIM + d0;
      u32v4 a = *(const u32v4*)&Kp[ga], b = *(const u32v4*)&Kp[ga + 4];
      u32v4 hi, lo;
      unpack8(a, b, hi, lo);
      *(u32v4*)&sKh[row * 72 + d0] = hi;
      *(u32v4*)&sKl[row * 72 + d0] = lo;
    }
    // ---- stage V^T [64 e][64 key]: thread: 4 key-rows x 2 e-cols ----
    {
      const int e2 = (tid & 31) * 2, p4 = (tid >> 5) * 4;
      u32v2 ld[4];
#pragma unroll
      for (int i = 0; i < 4; ++i)
        ld[i] = *(const u32v2*)&Vp[kvbase0 + (long)(c * 64 + p4 + i) * D_DIM + e2];
#pragma unroll
      for (int je = 0; je < 2; ++je) {
        u16v4 hv, lv;
#pragma unroll
        for (int i = 0; i < 4; ++i) {
          hv[i] = (unsigned short)(ld[i][je] & 0xffffu);
          lv[i] = (unsigned short)(ld[i][je] >> 16);
        }
        *(u16v4*)&sVTh[(e2 + je) * 72 + p4] = hv;
        *(u16v4*)&sVTl[(e2 + je) * 72 + p4] = lv;
      }
    }
    if (tid < 64) sMadd[tid] = (mask[seg * SEG_S + c * 64 + tid] == 0) ? -1e9f : 0.f;
    __syncthreads();

    fv4 madd[4];
#pragma unroll
    for (int kt = 0; kt < 4; ++kt) madd[kt] = *(const fv4*)&sMadd[kt * 16 + g * 4];

    // ---- S^T = K . Q^T (split 3-product) ----
    fv4 sc[4];
#pragma unroll
    for (int kt = 0; kt < 4; ++kt) {
      const int ro = (kt * 16 + ln16) * 72 + g * 8;
      bfv8 kh0 = *(const bfv8*)&sKh[ro], kh1 = *(const bfv8*)&sKh[ro + 32];
      bfv8 kl0 = *(const bfv8*)&sKl[ro], kl1 = *(const bfv8*)&sKl[ro + 32];
      fv4 s = {};
      s = __builtin_amdgcn_mfma_f32_16x16x32_bf16(kh0, qh[0], s, 0, 0, 0);
      s = __builtin_amdgcn_mfma_f32_16x16x32_bf16(kh1, qh[1], s, 0, 0, 0);
      s = __builtin_amdgcn_mfma_f32_16x16x32_bf16(kh0, ql[0], s, 0, 0, 0);
      s = __builtin_amdgcn_mfma_f32_16x16x32_bf16(kh1, ql[1], s, 0, 0, 0);
      s = __builtin_amdgcn_mfma_f32_16x16x32_bf16(kl0, qh[0], s, 0, 0, 0);
      s = __builtin_amdgcn_mfma_f32_16x16x32_bf16(kl1, qh[1], s, 0, 0, 0);
      sc[kt] = s;
    }
    // ---- online softmax (scale+mask folded into fma; defer-max THR=8) ----
    float pmax = -3.0e38f;
#pragma unroll
    for (int kt = 0; kt < 4; ++kt)
#pragma unroll
      for (int r = 0; r < 4; ++r) {
        const float v = __builtin_fmaf(sc[kt][r], 0.125f, madd[kt][r]);
        sc[kt][r] = v;
        pmax = fmaxf(pmax, v);
      }
    pmax = fmaxf(pmax, __shfl_xor(pmax, 16));
    pmax = fmaxf(pmax, __shfl_xor(pmax, 32));
    if (pmax > m_run + 8.f) {
      const float resc = __expf(m_run - pmax);
      l_run *= resc;
#pragma unroll
      for (int et = 0; et < 4; ++et)
#pragma unroll
        for (int r = 0; r < 4; ++r) O[et][r] *= resc;
      m_run = pmax;
    }
    // P (bf16-rounded, consistent with l-sum) -> per-wave LDS
    float psum = 0.f;
#pragma unroll
    for (int kt = 0; kt < 4; ++kt) {
      u16v4 pv;
#pragma unroll
      for (int r = 0; r < 4; ++r) {
        const unsigned short hb = f2bf(__expf(sc[kt][r] - m_run));
        pv[r] = hb;
        psum += bf2f(hb);
      }
      *(u16v4*)&sP[w][ln16 * 72 + kt * 16 + g * 4] = pv;
    }
    psum += __shfl_xor(psum, 16);
    psum += __shfl_xor(psum, 32);
    l_run += psum;

    bfv8 pf0 = *(const bfv8*)&sP[w][ln16 * 72 + g * 8];
    bfv8 pf1 = *(const bfv8*)&sP[w][ln16 * 72 + 32 + g * 8];
    // ---- O^T += V^T . P ----
#pragma unroll
    for (int et = 0; et < 4; ++et) {
      const int ro = (et * 16 + ln16) * 72 + g * 8;
      bfv8 vh0 = *(const bfv8*)&sVTh[ro], vh1 = *(const bfv8*)&sVTh[ro + 32];
      bfv8 vl0 = *(const bfv8*)&sVTl[ro], vl1 = *(const bfv8*)&sVTl[ro + 32];
      fv4 o = O[et];
      o = __builtin_amdgcn_mfma_f32_16x16x32_bf16(vh0, pf0, o, 0, 0, 0);
      o = __builtin_amdgcn_mfma_f32_16x16x32_bf16(vh1, pf1, o, 0, 0, 0);
      o = __builtin_amdgcn_mfma_f32_16x16x32_bf16(vl0, pf0, o, 0, 0, 0);
      o = __builtin_amdgcn_mfma_f32_16x16x32_bf16(vl1, pf1, o, 0, 0, 0);
      O[et] = o;
    }
  }

  // ---- memory-read term ----
  __syncthreads();
  {  // stage Mem^T [e][d] into sKh/sKl (fp32 source)
    const int e2 = (tid & 31) * 2, d4 = (tid >> 5) * 4;
    const float* Memp = Mem + (long)sh * 4096;
    fv2 ld[4];
#pragma unroll
    for (int i = 0; i < 4; ++i) ld[i] = *(const fv2*)&Memp[(d4 + i) * 64 + e2];
#pragma unroll
    for (int je = 0; je < 2; ++je) {
      u16v4 hv, lv;
#pragma unroll
      for (int i = 0; i < 4; ++i) {
        const unsigned short hb = f2bf(ld[i][je]);
        hv[i] = hb;
        lv[i] = f2bf(ld[i][je] - bf2f(hb));
      }
      *(u16v4*)&sKh[(e2 + je) * 72 + d4] = hv;
      *(u16v4*)&sKl[(e2 + je) * 72 + d4] = lv;
    }
  }
  if (tid < 64) {
    sZ[tid] = Zp[(long)sh * 64 + tid];
    sGate[tid] = 1.f / (1.f + __expf(-betas[h * 64 + tid]));
  }
  __syncthreads();

  // aq = elu(q)+1 in-register; denom = aq . z
  float dpart = 0.f;
#pragma unroll
  for (int dt = 0; dt < 2; ++dt) {
    u32v4 ah, al;
#pragma unroll
    for (int j = 0; j < 8; ++j) {
      const float x = (float)qh[dt][j] + (float)ql[dt][j];
      const float a = x > 0.f ? x + 1.f : __expf(x);
      dpart += a * sZ[dt * 32 + g * 8 + j];
      const unsigned short hb = f2bf(a);
      ((unsigned short*)&ah)[j] = hb;
      ((unsigned short*)&al)[j] = f2bf(a - bf2f(hb));
    }
    qh[dt] = __builtin_bit_cast(bfv8, ah);
    ql[dt] = __builtin_bit_cast(bfv8, al);
  }
  dpart += __shfl_xor(dpart, 16);
  dpart += __shfl_xor(dpart, 32);
  const float invden = 1.f / (dpart + 1e-9f);
  const float invl = 1.f / l_run;

  const long obase = (long)qglob * D_DIM + h * 64;
#pragma unroll
  for (int et = 0; et < 4; ++et) {
    const int ro = (et * 16 + ln16) * 72 + g * 8;
    bfv8 mh0 = *(const bfv8*)&sKh[ro], mh1 = *(const bfv8*)&sKh[ro + 32];
    bfv8 ml0 = *(const bfv8*)&sKl[ro], ml1 = *(const bfv8*)&sKl[ro + 32];
    fv4 o = {};
    o = __builtin_amdgcn_mfma_f32_16x16x32_bf16(mh0, qh[0], o, 0, 0, 0);
    o = __builtin_amdgcn_mfma_f32_16x16x32_bf16(mh1, qh[1], o, 0, 0, 0);
    o = __builtin_amdgcn_mfma_f32_16x16x32_bf16(mh0, ql[0], o, 0, 0, 0);
    o = __builtin_amdgcn_mfma_f32_16x16x32_bf16(mh1, ql[1], o, 0, 0, 0);
    o = __builtin_amdgcn_mfma_f32_16x16x32_bf16(ml0, qh[0], o, 0, 0, 0);
    o = __builtin_amdgcn_mfma_f32_16x16x32_bf16(ml1, qh[1], o, 0, 0, 0);
    const fv4 gt = *(const fv4*)&sGate[et * 16 + g * 4];
    u32v4 st;
#pragma unroll
    for (int r = 0; r < 4; ++r) {
      const float att = gt[r] * o[r] * invden + (1.f - gt[r]) * O[et][r] * invl;
      st[r] = packbf2(att);
    }
    *(u32v4*)&Op[obase + et * 16 + g * 4] = st;
  }
}

// ---------------- host launch: batch-tiled to bound workspace ----------------
extern "C" void kernel_launch(void* const* d_in, const int* in_sizes, int n_in,
                              void* d_out, int out_size, void* d_ws, size_t ws_size,
                              hipStream_t stream) {
  (void)in_sizes; (void)n_in; (void)out_size;
  const float* x     = (const float*)d_in[0];
  const int*   mask  = (const int*)d_in[1];
  const float* wq    = (const float*)d_in[2];
  const float* wk    = (const float*)d_in[3];
  const float* wv    = (const float*)d_in[4];
  const float* wo    = (const float*)d_in[5];
  const float* wob   = (const float*)d_in[6];
  const float* betas = (const float*)d_in[7];
  float* out = (float*)d_out;

  const size_t TOKB = (size_t)MB_TOK * D_DIM;
  char* ws = (char*)d_ws;
  size_t off = 0;
  auto alloc = [&](size_t bytes) {
    char* p = ws + off;
    off += (bytes + 255) & ~(size_t)255;
    return p;
  };
  unsigned* wsp[4];
  for (int i = 0; i < 4; ++i)
    wsp[i] = (unsigned*)alloc((size_t)D_DIM * D_DIM * 4);
  unsigned* xp = (unsigned*)alloc(TOKB * 4);
  unsigned* qp = (unsigned*)alloc(TOKB * 4);
  unsigned* kp = (unsigned*)alloc(TOKB * 4);
  unsigned* vp = (unsigned*)alloc(TOKB * 4);
  float* U   = (float*)alloc((size_t)NSEG * H_NUM * 4096 * 4);
  float* Mem = (float*)alloc((size_t)NSEG * H_NUM * 4096 * 4);
  float* Zs  = (float*)alloc((size_t)NSEG * H_NUM * 64 * 4);
  float* Zp  = (float*)alloc((size_t)NSEG * H_NUM * 64 * 4);
  unsigned* attp = xp;  // x dead after QKV GEMMs

  if (off > ws_size) return;

  const float* wsrc[4] = {wq, wk, wv, wo};
  for (int i = 0; i < 4; ++i)
    split_pack<<<1024, 256, 0, stream>>>(wsrc[i], wsp[i], D_DIM * D_DIM / 4);

  dim3 ggrid(D_DIM / 128, MB_TOK / 128);
  for (int b = 0; b < B_DIM; ++b) {
    const float* xb = x + (size_t)b * TOKB;
    const int* maskb = mask + (size_t)b * L_DIM;
    float* outb = out + (size_t)b * TOKB;

    split_pack<<<2048, 256, 0, stream>>>(xb, xp, (int)(TOKB / 4));

    gemm_bt_packed<<<ggrid, 256, 0, stream>>>(xp, wsp[0], nullptr, nullptr, qp,
                                              MB_TOK, D_DIM, D_DIM);
    gemm_bt_packed<<<ggrid, 256, 0, stream>>>(xp, wsp[1], nullptr, nullptr, kp,
                                              MB_TOK, D_DIM, D_DIM);
    gemm_bt_packed<<<ggrid, 256, 0, stream>>>(xp, wsp[2], nullptr, nullptr, vp,
                                              MB_TOK, D_DIM, D_DIM);

    seg_outer<<<NSEG * H_NUM, 256, 0, stream>>>(kp, vp, U, Zs);
    seg_prefix<<<H_NUM, 256, 0, stream>>>(U, Zs, Mem, Zp);

    attn_seg_mfma<<<NSEG * H_NUM * 4, 512, 0, stream>>>(qp, kp, vp, maskb, Mem, Zp,
                                                        betas, attp);

    gemm_bt_packed<<<ggrid, 256, 0, stream>>>(attp, wsp[3], outb, wob, nullptr,
                                              MB_TOK, D_DIM, D_DIM);
  }
}

// Round 6
// 1353.937 us; speedup vs baseline: 1.5550x; 1.1610x over previous
//
#include <hip/hip_runtime.h>

typedef float fv2 __attribute__((ext_vector_type(2)));
typedef float fv4 __attribute__((ext_vector_type(4)));
typedef __bf16 bfv8 __attribute__((ext_vector_type(8)));
typedef unsigned short u16v4 __attribute__((ext_vector_type(4)));
typedef unsigned short u16v8 __attribute__((ext_vector_type(8)));
typedef unsigned int u32v2 __attribute__((ext_vector_type(2)));
typedef unsigned int u32v4 __attribute__((ext_vector_type(4)));

#define B_DIM 4
#define L_DIM 8192
#define D_DIM 1024
#define H_NUM 16
#define NSEG 16
#define SEG_S 512
#define MB_TOK L_DIM  // rows per batch element: 8192

__device__ __forceinline__ unsigned short f2bf(float f) {
  unsigned u = __float_as_uint(f);
  u += 0x7fffu + ((u >> 16) & 1u);  // RNE
  return (unsigned short)(u >> 16);
}
__device__ __forceinline__ float bf2f(unsigned short h) {
  return __uint_as_float((unsigned)h << 16);
}
__device__ __forceinline__ unsigned packbf2(float v) {
  unsigned short hb = f2bf(v);
  unsigned short lb = f2bf(v - bf2f(hb));
  return (unsigned)hb | ((unsigned)lb << 16);
}
__device__ __forceinline__ float up_hi(unsigned u) { return __uint_as_float(u << 16); }
__device__ __forceinline__ float up_lo(unsigned u) { return __uint_as_float(u & 0xffff0000u); }

// unpack 8 packed elements (2 x u32v4) -> u32v4 of 8 hi-bf16 and 8 lo-bf16
__device__ __forceinline__ void unpack8(u32v4 a, u32v4 b, u32v4& hi, u32v4& lo) {
  hi[0] = __builtin_amdgcn_perm(a[1], a[0], 0x05040100u);
  hi[1] = __builtin_amdgcn_perm(a[3], a[2], 0x05040100u);
  hi[2] = __builtin_amdgcn_perm(b[1], b[0], 0x05040100u);
  hi[3] = __builtin_amdgcn_perm(b[3], b[2], 0x05040100u);
  lo[0] = __builtin_amdgcn_perm(a[1], a[0], 0x07060302u);
  lo[1] = __builtin_amdgcn_perm(a[3], a[2], 0x07060302u);
  lo[2] = __builtin_amdgcn_perm(b[1], b[0], 0x07060302u);
  lo[3] = __builtin_amdgcn_perm(b[3], b[2], 0x07060302u);
}

// ---------------- fp32 -> packed (hi|lo<<16) split ----------------
__global__ __launch_bounds__(256) void split_pack(
    const float* __restrict__ in, unsigned* __restrict__ outp, int n4) {
  int i = blockIdx.x * 256 + threadIdx.x;
  const int stride = gridDim.x * 256;
  for (; i < n4; i += stride) {
    fv4 v = reinterpret_cast<const fv4*>(in)[i];
    u32v4 p;
#pragma unroll
    for (int j = 0; j < 4; ++j) p[j] = packbf2(v[j]);
    reinterpret_cast<u32v4*>(outp)[i] = p;
  }
}

// ---------------- C[M,N] = A @ B^T, split-bf16 3-product MFMA, packed I/O ----------------
// T14 async-stage: global loads for step k+1 issue before the MFMA of step k.
#define GT_PAD 40
__global__ __launch_bounds__(256) void gemm_bt_packed(
    const unsigned* __restrict__ Ap, const unsigned* __restrict__ Bp,
    float* __restrict__ C, const float* __restrict__ bias,
    unsigned* __restrict__ Cp, int M, int N, int K) {
  __shared__ __bf16 sAh[128 * GT_PAD], sAl[128 * GT_PAD];
  __shared__ __bf16 sBh[128 * GT_PAD], sBl[128 * GT_PAD];
  const int tid = threadIdx.x;
  const int lane = tid & 63;
  const int wid = tid >> 6;
  const int wr = wid >> 1, wc = wid & 1;
  const int mBase = blockIdx.y * 128;
  const int nBase = blockIdx.x * 128;

  fv4 acc[4][4] = {};

  const int arowRd = wr * 64 + (lane & 15);
  const int browRd = wc * 64 + (lane & 15);
  const int koff = (lane >> 4) << 3;

  // staging coords: it0 rows 0..63, it1 rows 64..127
  const int srow0 = tid >> 2, srow1 = (256 + tid) >> 2, sch = tid & 3;
  const int ldo0 = srow0 * GT_PAD + sch * 8;
  const int ldo1 = srow1 * GT_PAD + sch * 8;

  u32v4 pa0[2], pa1[2], pb0[2], pb1[2];
  auto LOADK = [&](int k0) {
    const long ga0 = (long)(mBase + srow0) * K + k0 + sch * 8;
    const long ga1 = (long)(mBase + srow1) * K + k0 + sch * 8;
    const long gb0 = (long)(nBase + srow0) * K + k0 + sch * 8;
    const long gb1 = (long)(nBase + srow1) * K + k0 + sch * 8;
    pa0[0] = *(const u32v4*)&Ap[ga0]; pa0[1] = *(const u32v4*)&Ap[ga0 + 4];
    pa1[0] = *(const u32v4*)&Ap[ga1]; pa1[1] = *(const u32v4*)&Ap[ga1 + 4];
    pb0[0] = *(const u32v4*)&Bp[gb0]; pb0[1] = *(const u32v4*)&Bp[gb0 + 4];
    pb1[0] = *(const u32v4*)&Bp[gb1]; pb1[1] = *(const u32v4*)&Bp[gb1 + 4];
  };
  LOADK(0);

  for (int k0 = 0; k0 < K; k0 += 32) {
    __syncthreads();
    {
      u32v4 hi, lo;
      unpack8(pa0[0], pa0[1], hi, lo);
      *(u32v4*)&sAh[ldo0] = hi; *(u32v4*)&sAl[ldo0] = lo;
      unpack8(pb0[0], pb0[1], hi, lo);
      *(u32v4*)&sBh[ldo0] = hi; *(u32v4*)&sBl[ldo0] = lo;
      unpack8(pa1[0], pa1[1], hi, lo);
      *(u32v4*)&sAh[ldo1] = hi; *(u32v4*)&sAl[ldo1] = lo;
      unpack8(pb1[0], pb1[1], hi, lo);
      *(u32v4*)&sBh[ldo1] = hi; *(u32v4*)&sBl[ldo1] = lo;
    }
    if (k0 + 32 < K) LOADK(k0 + 32);  // async: latency hides under barrier+MFMA
    __syncthreads();
    bfv8 fah[4], fal[4], fbh[4], fbl[4];
#pragma unroll
    for (int i = 0; i < 4; ++i) {
      fah[i] = *(const bfv8*)&sAh[(arowRd + i * 16) * GT_PAD + koff];
      fal[i] = *(const bfv8*)&sAl[(arowRd + i * 16) * GT_PAD + koff];
      fbh[i] = *(const bfv8*)&sBh[(browRd + i * 16) * GT_PAD + koff];
      fbl[i] = *(const bfv8*)&sBl[(browRd + i * 16) * GT_PAD + koff];
    }
#pragma unroll
    for (int i = 0; i < 4; ++i)
#pragma unroll
      for (int j = 0; j < 4; ++j) {
        acc[i][j] = __builtin_amdgcn_mfma_f32_16x16x32_bf16(fah[i], fbh[j], acc[i][j], 0, 0, 0);
        acc[i][j] = __builtin_amdgcn_mfma_f32_16x16x32_bf16(fah[i], fbl[j], acc[i][j], 0, 0, 0);
        acc[i][j] = __builtin_amdgcn_mfma_f32_16x16x32_bf16(fal[i], fbh[j], acc[i][j], 0, 0, 0);
      }
  }

  // C/D layout (verified m89): col = lane&15, row = 4*(lane>>4) + reg
  const int crow0 = mBase + wr * 64 + ((lane >> 4) << 2);
  const int ccol0 = nBase + wc * 64 + (lane & 15);
  if (Cp) {
#pragma unroll
    for (int j = 0; j < 4; ++j) {
      const int col = ccol0 + j * 16;
#pragma unroll
      for (int i = 0; i < 4; ++i) {
        const long rb = (long)(crow0 + i * 16) * N + col;
#pragma unroll
        for (int r = 0; r < 4; ++r)
          Cp[rb + (long)r * N] = packbf2(acc[i][j][r]);
      }
    }
  } else {
#pragma unroll
    for (int j = 0; j < 4; ++j) {
      const int col = ccol0 + j * 16;
      const float bv = bias ? bias[col] : 0.f;
#pragma unroll
      for (int i = 0; i < 4; ++i) {
        const long rb = (long)(crow0 + i * 16) * N + col;
#pragma unroll
        for (int r = 0; r < 4; ++r)
          C[rb + (long)r * N] = acc[i][j][r] + bv;
      }
    }
  }
}

// ---------------- per-(seg,h) outer products, MFMA-ized ----------------
// U[d][e] = sum_s ak[s,d]*v[s,e] with ak = elu(k)+1; Zs[d] = sum_s ak[s,d].
// Stage akT [d][s] and vT [e][s] (transposed quad-pack), split-bf16 3-product MFMA.
__global__ __launch_bounds__(256) void seg_outer_mfma(
    const unsigned* __restrict__ Kp, const unsigned* __restrict__ Vp,
    float* __restrict__ U, float* __restrict__ Zs) {
  __shared__ __bf16 sAh[64 * 72], sAl[64 * 72];  // akT [d][s]
  __shared__ __bf16 sVh[64 * 72], sVl[64 * 72];  // vT  [e][s]
  __shared__ float sZf[64];
  const int shd = blockIdx.x;
  const int seg = shd >> 4, h = shd & 15;
  const int tid = threadIdx.x;
  const int lane = tid & 63, w = tid >> 6;
  const int g = lane >> 4, ln16 = lane & 15;
  const long base = ((long)seg * SEG_S) * D_DIM + h * 64;

  if (tid < 64) sZf[tid] = 0.f;
  fv4 acc[4] = {};         // wave w owns d-rows [w*16, w*16+16), all 64 e via 4 tiles
  fv2 zpart = {0.f, 0.f};
  const int dcol = (tid & 31) * 2, s8 = (tid >> 5) * 8;

  for (int c = 0; c < 8; ++c) {
    __syncthreads();
    u32v2 kld[8], vld[8];
#pragma unroll
    for (int i = 0; i < 8; ++i) {
      const long gidx = base + (long)(c * 64 + s8 + i) * D_DIM + dcol;
      kld[i] = *(const u32v2*)&Kp[gidx];
      vld[i] = *(const u32v2*)&Vp[gidx];
    }
#pragma unroll
    for (int j = 0; j < 2; ++j) {
      u16v8 ah, al, vh, vl;
#pragma unroll
      for (int i = 0; i < 8; ++i) {
        const float kv = up_hi(kld[i][j]) + up_lo(kld[i][j]);
        const float a = kv > 0.f ? kv + 1.f : __expf(kv);
        zpart[j] += a;
        const unsigned short hb = f2bf(a);
        ah[i] = hb;
        al[i] = f2bf(a - bf2f(hb));
        vh[i] = (unsigned short)(vld[i][j] & 0xffffu);
        vl[i] = (unsigned short)(vld[i][j] >> 16);
      }
      *(u16v8*)&sAh[(dcol + j) * 72 + s8] = ah;
      *(u16v8*)&sAl[(dcol + j) * 72 + s8] = al;
      *(u16v8*)&sVh[(dcol + j) * 72 + s8] = vh;
      *(u16v8*)&sVl[(dcol + j) * 72 + s8] = vl;
    }
    __syncthreads();
#pragma unroll
    for (int kf = 0; kf < 2; ++kf) {
      const int so = kf * 32 + g * 8;
      bfv8 aH = *(const bfv8*)&sAh[(w * 16 + ln16) * 72 + so];
      bfv8 aL = *(const bfv8*)&sAl[(w * 16 + ln16) * 72 + so];
#pragma unroll
      for (int et = 0; et < 4; ++et) {
        bfv8 bH = *(const bfv8*)&sVh[(et * 16 + ln16) * 72 + so];
        bfv8 bL = *(const bfv8*)&sVl[(et * 16 + ln16) * 72 + so];
        acc[et] = __builtin_amdgcn_mfma_f32_16x16x32_bf16(aH, bH, acc[et], 0, 0, 0);
        acc[et] = __builtin_amdgcn_mfma_f32_16x16x32_bf16(aH, bL, acc[et], 0, 0, 0);
        acc[et] = __builtin_amdgcn_mfma_f32_16x16x32_bf16(aL, bH, acc[et], 0, 0, 0);
      }
    }
  }
  atomicAdd(&sZf[dcol], zpart[0]);
  atomicAdd(&sZf[dcol + 1], zpart[1]);
  __syncthreads();

  const long ub = (long)shd * 4096;
#pragma unroll
  for (int et = 0; et < 4; ++et)
#pragma unroll
    for (int r = 0; r < 4; ++r)
      U[ub + (long)(w * 16 + g * 4 + r) * 64 + et * 16 + ln16] = acc[et][r];
  if (tid < 64) Zs[(long)shd * 64 + tid] = sZf[tid];
}

// ---------------- exclusive prefix over segments ----------------
__global__ __launch_bounds__(256) void seg_prefix(
    const float* __restrict__ U, const float* __restrict__ Zs,
    float* __restrict__ Mem, float* __restrict__ Zp) {
  const int h = blockIdx.x;   // 0..15
  const int jc = blockIdx.y;  // 0..7
  const int tid = threadIdx.x;
  for (int j = jc * 512 + tid; j < jc * 512 + 512; j += 256) {
    float run = 0.f;
#pragma unroll
    for (int t = 0; t < NSEG; ++t) {
      const long idx = ((long)(t * 16 + h)) * 4096 + j;
      Mem[idx] = run;
      run += U[idx];
    }
  }
  if (jc == 0 && tid < 64) {
    float run = 0.f;
#pragma unroll
    for (int t = 0; t < NSEG; ++t) {
      const long idx = ((long)(t * 16 + h)) * 64 + tid;
      Zp[idx] = run;
      run += Zs[idx];
    }
  }
}

// ---------------- MFMA segment attention: 512 thr, 8 waves, 16 q/wave ----------------
// V kept hi-plane only (bf16): PV 2 MFMAs/et; LDS 47KB -> 3 blocks/CU.
__global__ __launch_bounds__(512, 4) void attn_seg_mfma(
    const unsigned* __restrict__ Qp, const unsigned* __restrict__ Kp,
    const unsigned* __restrict__ Vp, const int* __restrict__ mask,
    const float* __restrict__ Mem, const float* __restrict__ Zp,
    const float* __restrict__ betas, unsigned* __restrict__ Op) {
  __shared__ __bf16 sKh[64 * 72], sKl[64 * 72];  // K chunk [key][d]; later Mem^T [e][d]
  __shared__ __bf16 sVTh[64 * 72];               // V^T [e][key] (hi only)
  __shared__ __bf16 sP[8][16 * 72];              // per-wave P (bf16) [q][key]
  __shared__ float sMadd[64], sZ[64], sGate[64];

  const int bx = blockIdx.x;
  const int qblk = bx & 3, h = (bx >> 2) & 15, seg = bx >> 6;
  const int sh = seg * 16 + h;
  const int tid = threadIdx.x;
  const int lane = tid & 63, w = tid >> 6;
  const int g = lane >> 4, ln16 = lane & 15;

  // ---- Q fragments (16 queries per wave), packed loads ----
  const int qglob = seg * SEG_S + qblk * 128 + w * 16 + ln16;
  const long qbase = (long)qglob * D_DIM + h * 64;
  bfv8 qh[2], ql[2];
#pragma unroll
  for (int dt = 0; dt < 2; ++dt) {
    u32v4 a = *(const u32v4*)&Qp[qbase + dt * 32 + g * 8];
    u32v4 b = *(const u32v4*)&Qp[qbase + dt * 32 + g * 8 + 4];
    u32v4 hi, lo;
    unpack8(a, b, hi, lo);
    qh[dt] = __builtin_bit_cast(bfv8, hi);
    ql[dt] = __builtin_bit_cast(bfv8, lo);
  }

  fv4 O[4] = {};
  float m_run = -1e30f, l_run = 0.f;
  const long kvbase0 = (long)(seg * SEG_S) * D_DIM + h * 64;

  for (int c = 0; c < 8; ++c) {
    __syncthreads();
    // ---- stage K [64 key][64 d]: 512 thr, 8 els each ----
    {
      const int row = tid >> 3, d0 = (tid & 7) * 8;
      const long ga = kvbase0 + (long)(c * 64 + row) * D_DIM + d0;
      u32v4 a = *(const u32v4*)&Kp[ga], b = *(const u32v4*)&Kp[ga + 4];
      u32v4 hi, lo;
      unpack8(a, b, hi, lo);
      *(u32v4*)&sKh[row * 72 + d0] = hi;
      *(u32v4*)&sKl[row * 72 + d0] = lo;
    }
    // ---- stage V^T [64 e][64 key] hi-plane only ----
    {
      const int e2 = (tid & 31) * 2, p4 = (tid >> 5) * 4;
      u32v2 ld[4];
#pragma unroll
      for (int i = 0; i < 4; ++i)
        ld[i] = *(const u32v2*)&Vp[kvbase0 + (long)(c * 64 + p4 + i) * D_DIM + e2];
#pragma unroll
      for (int je = 0; je < 2; ++je) {
        u16v4 hv;
#pragma unroll
        for (int i = 0; i < 4; ++i) hv[i] = (unsigned short)(ld[i][je] & 0xffffu);
        *(u16v4*)&sVTh[(e2 + je) * 72 + p4] = hv;
      }
    }
    if (tid < 64) sMadd[tid] = (mask[seg * SEG_S + c * 64 + tid] == 0) ? -1e9f : 0.f;
    __syncthreads();

    fv4 madd[4];
#pragma unroll
    for (int kt = 0; kt < 4; ++kt) madd[kt] = *(const fv4*)&sMadd[kt * 16 + g * 4];

    // ---- S^T = K . Q^T (split 3-product) ----
    fv4 sc[4];
#pragma unroll
    for (int kt = 0; kt < 4; ++kt) {
      const int ro = (kt * 16 + ln16) * 72 + g * 8;
      bfv8 kh0 = *(const bfv8*)&sKh[ro], kh1 = *(const bfv8*)&sKh[ro + 32];
      bfv8 kl0 = *(const bfv8*)&sKl[ro], kl1 = *(const bfv8*)&sKl[ro + 32];
      fv4 s = {};
      s = __builtin_amdgcn_mfma_f32_16x16x32_bf16(kh0, qh[0], s, 0, 0, 0);
      s = __builtin_amdgcn_mfma_f32_16x16x32_bf16(kh1, qh[1], s, 0, 0, 0);
      s = __builtin_amdgcn_mfma_f32_16x16x32_bf16(kh0, ql[0], s, 0, 0, 0);
      s = __builtin_amdgcn_mfma_f32_16x16x32_bf16(kh1, ql[1], s, 0, 0, 0);
      s = __builtin_amdgcn_mfma_f32_16x16x32_bf16(kl0, qh[0], s, 0, 0, 0);
      s = __builtin_amdgcn_mfma_f32_16x16x32_bf16(kl1, qh[1], s, 0, 0, 0);
      sc[kt] = s;
    }
    // ---- online softmax (defer-max THR=8) ----
    float pmax = -3.0e38f;
#pragma unroll
    for (int kt = 0; kt < 4; ++kt)
#pragma unroll
      for (int r = 0; r < 4; ++r) {
        const float v = __builtin_fmaf(sc[kt][r], 0.125f, madd[kt][r]);
        sc[kt][r] = v;
        pmax = fmaxf(pmax, v);
      }
    pmax = fmaxf(pmax, __shfl_xor(pmax, 16));
    pmax = fmaxf(pmax, __shfl_xor(pmax, 32));
    if (pmax > m_run + 8.f) {
      const float resc = __expf(m_run - pmax);
      l_run *= resc;
#pragma unroll
      for (int et = 0; et < 4; ++et)
#pragma unroll
        for (int r = 0; r < 4; ++r) O[et][r] *= resc;
      m_run = pmax;
    }
    float psum = 0.f;
#pragma unroll
    for (int kt = 0; kt < 4; ++kt) {
      u16v4 pv;
#pragma unroll
      for (int r = 0; r < 4; ++r) {
        const unsigned short hb = f2bf(__expf(sc[kt][r] - m_run));
        pv[r] = hb;
        psum += bf2f(hb);
      }
      *(u16v4*)&sP[w][ln16 * 72 + kt * 16 + g * 4] = pv;
    }
    psum += __shfl_xor(psum, 16);
    psum += __shfl_xor(psum, 32);
    l_run += psum;

    bfv8 pf0 = *(const bfv8*)&sP[w][ln16 * 72 + g * 8];
    bfv8 pf1 = *(const bfv8*)&sP[w][ln16 * 72 + 32 + g * 8];
    // ---- O^T += V^T . P (V hi only) ----
#pragma unroll
    for (int et = 0; et < 4; ++et) {
      const int ro = (et * 16 + ln16) * 72 + g * 8;
      bfv8 vh0 = *(const bfv8*)&sVTh[ro], vh1 = *(const bfv8*)&sVTh[ro + 32];
      fv4 o = O[et];
      o = __builtin_amdgcn_mfma_f32_16x16x32_bf16(vh0, pf0, o, 0, 0, 0);
      o = __builtin_amdgcn_mfma_f32_16x16x32_bf16(vh1, pf1, o, 0, 0, 0);
      O[et] = o;
    }
  }

  // ---- memory-read term ----
  __syncthreads();
  {  // stage Mem^T [e][d] into sKh/sKl (fp32 source)
    const int e2 = (tid & 31) * 2, d4 = (tid >> 5) * 4;
    const float* Memp = Mem + (long)sh * 4096;
    fv2 ld[4];
#pragma unroll
    for (int i = 0; i < 4; ++i) ld[i] = *(const fv2*)&Memp[(d4 + i) * 64 + e2];
#pragma unroll
    for (int je = 0; je < 2; ++je) {
      u16v4 hv, lv;
#pragma unroll
      for (int i = 0; i < 4; ++i) {
        const unsigned short hb = f2bf(ld[i][je]);
        hv[i] = hb;
        lv[i] = f2bf(ld[i][je] - bf2f(hb));
      }
      *(u16v4*)&sKh[(e2 + je) * 72 + d4] = hv;
      *(u16v4*)&sKl[(e2 + je) * 72 + d4] = lv;
    }
  }
  if (tid < 64) {
    sZ[tid] = Zp[(long)sh * 64 + tid];
    sGate[tid] = 1.f / (1.f + __expf(-betas[h * 64 + tid]));
  }
  __syncthreads();

  // aq = elu(q)+1 in-register; denom = aq . z
  float dpart = 0.f;
#pragma unroll
  for (int dt = 0; dt < 2; ++dt) {
    u32v4 ah, al;
#pragma unroll
    for (int j = 0; j < 8; ++j) {
      const float x = (float)qh[dt][j] + (float)ql[dt][j];
      const float a = x > 0.f ? x + 1.f : __expf(x);
      dpart += a * sZ[dt * 32 + g * 8 + j];
      const unsigned short hb = f2bf(a);
      ((unsigned short*)&ah)[j] = hb;
      ((unsigned short*)&al)[j] = f2bf(a - bf2f(hb));
    }
    qh[dt] = __builtin_bit_cast(bfv8, ah);
    ql[dt] = __builtin_bit_cast(bfv8, al);
  }
  dpart += __shfl_xor(dpart, 16);
  dpart += __shfl_xor(dpart, 32);
  const float invden = 1.f / (dpart + 1e-9f);
  const float invl = 1.f / l_run;

  const long obase = (long)qglob * D_DIM + h * 64;
#pragma unroll
  for (int et = 0; et < 4; ++et) {
    const int ro = (et * 16 + ln16) * 72 + g * 8;
    bfv8 mh0 = *(const bfv8*)&sKh[ro], mh1 = *(const bfv8*)&sKh[ro + 32];
    bfv8 ml0 = *(const bfv8*)&sKl[ro], ml1 = *(const bfv8*)&sKl[ro + 32];
    fv4 o = {};
    o = __builtin_amdgcn_mfma_f32_16x16x32_bf16(mh0, qh[0], o, 0, 0, 0);
    o = __builtin_amdgcn_mfma_f32_16x16x32_bf16(mh1, qh[1], o, 0, 0, 0);
    o = __builtin_amdgcn_mfma_f32_16x16x32_bf16(mh0, ql[0], o, 0, 0, 0);
    o = __builtin_amdgcn_mfma_f32_16x16x32_bf16(mh1, ql[1], o, 0, 0, 0);
    o = __builtin_amdgcn_mfma_f32_16x16x32_bf16(ml0, qh[0], o, 0, 0, 0);
    o = __builtin_amdgcn_mfma_f32_16x16x32_bf16(ml1, qh[1], o, 0, 0, 0);
    const fv4 gt = *(const fv4*)&sGate[et * 16 + g * 4];
    u32v4 st;
#pragma unroll
    for (int r = 0; r < 4; ++r) {
      const float att = gt[r] * o[r] * invden + (1.f - gt[r]) * O[et][r] * invl;
      st[r] = packbf2(att);
    }
    *(u32v4*)&Op[obase + et * 16 + g * 4] = st;
  }
}

// ---------------- host launch: batch-tiled to bound workspace ----------------
extern "C" void kernel_launch(void* const* d_in, const int* in_sizes, int n_in,
                              void* d_out, int out_size, void* d_ws, size_t ws_size,
                              hipStream_t stream) {
  (void)in_sizes; (void)n_in; (void)out_size;
  const float* x     = (const float*)d_in[0];
  const int*   mask  = (const int*)d_in[1];
  const float* wq    = (const float*)d_in[2];
  const float* wk    = (const float*)d_in[3];
  const float* wv    = (const float*)d_in[4];
  const float* wo    = (const float*)d_in[5];
  const float* wob   = (const float*)d_in[6];
  const float* betas = (const float*)d_in[7];
  float* out = (float*)d_out;

  const size_t TOKB = (size_t)MB_TOK * D_DIM;
  char* ws = (char*)d_ws;
  size_t off = 0;
  auto alloc = [&](size_t bytes) {
    char* p = ws + off;
    off += (bytes + 255) & ~(size_t)255;
    return p;
  };
  unsigned* wsp[4];
  for (int i = 0; i < 4; ++i)
    wsp[i] = (unsigned*)alloc((size_t)D_DIM * D_DIM * 4);
  unsigned* xp = (unsigned*)alloc(TOKB * 4);
  unsigned* qp = (unsigned*)alloc(TOKB * 4);
  unsigned* kp = (unsigned*)alloc(TOKB * 4);
  unsigned* vp = (unsigned*)alloc(TOKB * 4);
  float* U   = (float*)alloc((size_t)NSEG * H_NUM * 4096 * 4);
  float* Mem = (float*)alloc((size_t)NSEG * H_NUM * 4096 * 4);
  float* Zs  = (float*)alloc((size_t)NSEG * H_NUM * 64 * 4);
  float* Zp  = (float*)alloc((size_t)NSEG * H_NUM * 64 * 4);
  unsigned* attp = xp;  // x dead after QKV GEMMs

  if (off > ws_size) return;

  const float* wsrc[4] = {wq, wk, wv, wo};
  for (int i = 0; i < 4; ++i)
    split_pack<<<1024, 256, 0, stream>>>(wsrc[i], wsp[i], D_DIM * D_DIM / 4);

  dim3 ggrid(D_DIM / 128, MB_TOK / 128);
  dim3 pgrid(H_NUM, 8);
  for (int b = 0; b < B_DIM; ++b) {
    const float* xb = x + (size_t)b * TOKB;
    const int* maskb = mask + (size_t)b * L_DIM;
    float* outb = out + (size_t)b * TOKB;

    split_pack<<<2048, 256, 0, stream>>>(xb, xp, (int)(TOKB / 4));

    gemm_bt_packed<<<ggrid, 256, 0, stream>>>(xp, wsp[0], nullptr, nullptr, qp,
                                              MB_TOK, D_DIM, D_DIM);
    gemm_bt_packed<<<ggrid, 256, 0, stream>>>(xp, wsp[1], nullptr, nullptr, kp,
                                              MB_TOK, D_DIM, D_DIM);
    gemm_bt_packed<<<ggrid, 256, 0, stream>>>(xp, wsp[2], nullptr, nullptr, vp,
                                              MB_TOK, D_DIM, D_DIM);

    seg_outer_mfma<<<NSEG * H_NUM, 256, 0, stream>>>(kp, vp, U, Zs);
    seg_prefix<<<pgrid, 256, 0, stream>>>(U, Zs, Mem, Zp);

    attn_seg_mfma<<<NSEG * H_NUM * 4, 512, 0, stream>>>(qp, kp, vp, maskb, Mem, Zp,
                                                        betas, attp);

    gemm_bt_packed<<<ggrid, 256, 0, stream>>>(attp, wsp[3], outb, wob, nullptr,
                                              MB_TOK, D_DIM, D_DIM);
  }
}

// Round 7
// 1318.976 us; speedup vs baseline: 1.5962x; 1.0265x over previous
//
#include <hip/hip_runtime.h>

typedef float fv2 __attribute__((ext_vector_type(2)));
typedef float fv4 __attribute__((ext_vector_type(4)));
typedef __bf16 bfv8 __attribute__((ext_vector_type(8)));
typedef unsigned short u16v4 __attribute__((ext_vector_type(4)));
typedef unsigned short u16v8 __attribute__((ext_vector_type(8)));
typedef unsigned int u32v2 __attribute__((ext_vector_type(2)));
typedef unsigned int u32v4 __attribute__((ext_vector_type(4)));

#define B_DIM 4
#define L_DIM 8192
#define D_DIM 1024
#define H_NUM 16
#define NSEG 16
#define SEG_S 512
#define MB_TOK L_DIM  // rows per batch element: 8192

__device__ __forceinline__ unsigned short f2bf(float f) {
  unsigned u = __float_as_uint(f);
  u += 0x7fffu + ((u >> 16) & 1u);  // RNE
  return (unsigned short)(u >> 16);
}
__device__ __forceinline__ float bf2f(unsigned short h) {
  return __uint_as_float((unsigned)h << 16);
}
__device__ __forceinline__ unsigned packbf2(float v) {
  unsigned short hb = f2bf(v);
  unsigned short lb = f2bf(v - bf2f(hb));
  return (unsigned)hb | ((unsigned)lb << 16);
}
__device__ __forceinline__ float up_hi(unsigned u) { return __uint_as_float(u << 16); }
__device__ __forceinline__ float up_lo(unsigned u) { return __uint_as_float(u & 0xffff0000u); }

// unpack 8 packed elements (2 x u32v4) -> u32v4 of 8 hi-bf16 and 8 lo-bf16
__device__ __forceinline__ void unpack8(u32v4 a, u32v4 b, u32v4& hi, u32v4& lo) {
  hi[0] = __builtin_amdgcn_perm(a[1], a[0], 0x05040100u);
  hi[1] = __builtin_amdgcn_perm(a[3], a[2], 0x05040100u);
  hi[2] = __builtin_amdgcn_perm(b[1], b[0], 0x05040100u);
  hi[3] = __builtin_amdgcn_perm(b[3], b[2], 0x05040100u);
  lo[0] = __builtin_amdgcn_perm(a[1], a[0], 0x07060302u);
  lo[1] = __builtin_amdgcn_perm(a[3], a[2], 0x07060302u);
  lo[2] = __builtin_amdgcn_perm(b[1], b[0], 0x07060302u);
  lo[3] = __builtin_amdgcn_perm(b[3], b[2], 0x07060302u);
}

// ---------------- fp32 -> packed (hi|lo<<16) split ----------------
__global__ __launch_bounds__(256) void split_pack(
    const float* __restrict__ in, unsigned* __restrict__ outp, int n4) {
  int i = blockIdx.x * 256 + threadIdx.x;
  const int stride = gridDim.x * 256;
  for (; i < n4; i += stride) {
    fv4 v = reinterpret_cast<const fv4*>(in)[i];
    u32v4 p;
#pragma unroll
    for (int j = 0; j < 4; ++j) p[j] = packbf2(v[j]);
    reinterpret_cast<u32v4*>(outp)[i] = p;
  }
}

// ---------------- C[M,N] = A @ B^T, split-bf16 3-product MFMA, packed I/O ----------------
// T14 async-stage: global loads for step k+1 issue before the MFMA of step k.
#define GT_PAD 40
__global__ __launch_bounds__(256) void gemm_bt_packed(
    const unsigned* __restrict__ Ap, const unsigned* __restrict__ Bp,
    float* __restrict__ C, const float* __restrict__ bias,
    unsigned* __restrict__ Cp, int M, int N, int K) {
  __shared__ __bf16 sAh[128 * GT_PAD], sAl[128 * GT_PAD];
  __shared__ __bf16 sBh[128 * GT_PAD], sBl[128 * GT_PAD];
  const int tid = threadIdx.x;
  const int lane = tid & 63;
  const int wid = tid >> 6;
  const int wr = wid >> 1, wc = wid & 1;
  const int mBase = blockIdx.y * 128;
  const int nBase = blockIdx.x * 128;

  fv4 acc[4][4] = {};

  const int arowRd = wr * 64 + (lane & 15);
  const int browRd = wc * 64 + (lane & 15);
  const int koff = (lane >> 4) << 3;

  const int srow0 = tid >> 2, srow1 = (256 + tid) >> 2, sch = tid & 3;
  const int ldo0 = srow0 * GT_PAD + sch * 8;
  const int ldo1 = srow1 * GT_PAD + sch * 8;

  u32v4 pa0[2], pa1[2], pb0[2], pb1[2];
  auto LOADK = [&](int k0) {
    const long ga0 = (long)(mBase + srow0) * K + k0 + sch * 8;
    const long ga1 = (long)(mBase + srow1) * K + k0 + sch * 8;
    const long gb0 = (long)(nBase + srow0) * K + k0 + sch * 8;
    const long gb1 = (long)(nBase + srow1) * K + k0 + sch * 8;
    pa0[0] = *(const u32v4*)&Ap[ga0]; pa0[1] = *(const u32v4*)&Ap[ga0 + 4];
    pa1[0] = *(const u32v4*)&Ap[ga1]; pa1[1] = *(const u32v4*)&Ap[ga1 + 4];
    pb0[0] = *(const u32v4*)&Bp[gb0]; pb0[1] = *(const u32v4*)&Bp[gb0 + 4];
    pb1[0] = *(const u32v4*)&Bp[gb1]; pb1[1] = *(const u32v4*)&Bp[gb1 + 4];
  };
  LOADK(0);

  for (int k0 = 0; k0 < K; k0 += 32) {
    __syncthreads();
    {
      u32v4 hi, lo;
      unpack8(pa0[0], pa0[1], hi, lo);
      *(u32v4*)&sAh[ldo0] = hi; *(u32v4*)&sAl[ldo0] = lo;
      unpack8(pb0[0], pb0[1], hi, lo);
      *(u32v4*)&sBh[ldo0] = hi; *(u32v4*)&sBl[ldo0] = lo;
      unpack8(pa1[0], pa1[1], hi, lo);
      *(u32v4*)&sAh[ldo1] = hi; *(u32v4*)&sAl[ldo1] = lo;
      unpack8(pb1[0], pb1[1], hi, lo);
      *(u32v4*)&sBh[ldo1] = hi; *(u32v4*)&sBl[ldo1] = lo;
    }
    if (k0 + 32 < K) LOADK(k0 + 32);  // latency hides under barrier+MFMA
    __syncthreads();
    bfv8 fah[4], fal[4], fbh[4], fbl[4];
#pragma unroll
    for (int i = 0; i < 4; ++i) {
      fah[i] = *(const bfv8*)&sAh[(arowRd + i * 16) * GT_PAD + koff];
      fal[i] = *(const bfv8*)&sAl[(arowRd + i * 16) * GT_PAD + koff];
      fbh[i] = *(const bfv8*)&sBh[(browRd + i * 16) * GT_PAD + koff];
      fbl[i] = *(const bfv8*)&sBl[(browRd + i * 16) * GT_PAD + koff];
    }
#pragma unroll
    for (int i = 0; i < 4; ++i)
#pragma unroll
      for (int j = 0; j < 4; ++j) {
        acc[i][j] = __builtin_amdgcn_mfma_f32_16x16x32_bf16(fah[i], fbh[j], acc[i][j], 0, 0, 0);
        acc[i][j] = __builtin_amdgcn_mfma_f32_16x16x32_bf16(fah[i], fbl[j], acc[i][j], 0, 0, 0);
        acc[i][j] = __builtin_amdgcn_mfma_f32_16x16x32_bf16(fal[i], fbh[j], acc[i][j], 0, 0, 0);
      }
  }

  // C/D layout (verified m89): col = lane&15, row = 4*(lane>>4) + reg
  const int crow0 = mBase + wr * 64 + ((lane >> 4) << 2);
  const int ccol0 = nBase + wc * 64 + (lane & 15);
  if (Cp) {
#pragma unroll
    for (int j = 0; j < 4; ++j) {
      const int col = ccol0 + j * 16;
#pragma unroll
      for (int i = 0; i < 4; ++i) {
        const long rb = (long)(crow0 + i * 16) * N + col;
#pragma unroll
        for (int r = 0; r < 4; ++r)
          Cp[rb + (long)r * N] = packbf2(acc[i][j][r]);
      }
    }
  } else {
#pragma unroll
    for (int j = 0; j < 4; ++j) {
      const int col = ccol0 + j * 16;
      const float bv = bias ? bias[col] : 0.f;
#pragma unroll
      for (int i = 0; i < 4; ++i) {
        const long rb = (long)(crow0 + i * 16) * N + col;
#pragma unroll
        for (int r = 0; r < 4; ++r)
          C[rb + (long)r * N] = acc[i][j][r] + bv;
      }
    }
  }
}

// ---------------- per-(seg,h) outer products, MFMA-ized, swizzled LDS ----------------
// U[d][e] = sum_s ak[s,d]*v[s,e] with ak = elu(k)+1; Zs[d] = sum_s ak[s,d].
// LDS tiles [row][64 s], stride 64, col ^= 8*(row&7) (T2-style, conflict-free).
__global__ __launch_bounds__(256) void seg_outer_mfma(
    const unsigned* __restrict__ Kp, const unsigned* __restrict__ Vp,
    float* __restrict__ U, float* __restrict__ Zs) {
  __shared__ __bf16 sAh[64 * 64], sAl[64 * 64];  // akT [d][s]
  __shared__ __bf16 sVh[64 * 64], sVl[64 * 64];  // vT  [e][s]
  __shared__ float sZf[64];
  const int shd = blockIdx.x;
  const int seg = shd >> 4, h = shd & 15;
  const int tid = threadIdx.x;
  const int lane = tid & 63, w = tid >> 6;
  const int g = lane >> 4, ln16 = lane & 15;
  const long base = ((long)seg * SEG_S) * D_DIM + h * 64;

  if (tid < 64) sZf[tid] = 0.f;
  fv4 acc[4] = {};  // wave w owns d-rows [w*16, w*16+16), 4 e-tiles of 16
  float zacc = 0.f;
  const int strow = tid & 63;            // d (for akT) and e (for vT)
  const int sg0 = (tid >> 6) * 16;       // 16 s-values per thread
  const int wsw = (strow & 7) << 3;
  const int rsw = (ln16 & 7) << 3;

  for (int c = 0; c < 8; ++c) {
    __syncthreads();
#pragma unroll
    for (int jj = 0; jj < 2; ++jj) {
      u16v8 ah, al, vh, vl;
#pragma unroll
      for (int i = 0; i < 8; ++i) {
        const long gidx = base + (long)(c * 64 + sg0 + jj * 8 + i) * D_DIM + strow;
        const unsigned ku = Kp[gidx];
        const unsigned vu = Vp[gidx];
        const float kv = up_hi(ku) + up_lo(ku);
        const float a = kv > 0.f ? kv + 1.f : __expf(kv);
        zacc += a;
        const unsigned short hb = f2bf(a);
        ah[i] = hb;
        al[i] = f2bf(a - bf2f(hb));
        vh[i] = (unsigned short)(vu & 0xffffu);
        vl[i] = (unsigned short)(vu >> 16);
      }
      const int col = (sg0 + jj * 8) ^ wsw;
      *(u16v8*)&sAh[strow * 64 + col] = ah;
      *(u16v8*)&sAl[strow * 64 + col] = al;
      *(u16v8*)&sVh[strow * 64 + col] = vh;
      *(u16v8*)&sVl[strow * 64 + col] = vl;
    }
    __syncthreads();
#pragma unroll
    for (int kf = 0; kf < 2; ++kf) {
      const int so = (kf * 32 + g * 8) ^ rsw;
      bfv8 aH = *(const bfv8*)&sAh[(w * 16 + ln16) * 64 + so];
      bfv8 aL = *(const bfv8*)&sAl[(w * 16 + ln16) * 64 + so];
#pragma unroll
      for (int et = 0; et < 4; ++et) {
        bfv8 bH = *(const bfv8*)&sVh[(et * 16 + ln16) * 64 + so];
        bfv8 bL = *(const bfv8*)&sVl[(et * 16 + ln16) * 64 + so];
        acc[et] = __builtin_amdgcn_mfma_f32_16x16x32_bf16(aH, bH, acc[et], 0, 0, 0);
        acc[et] = __builtin_amdgcn_mfma_f32_16x16x32_bf16(aH, bL, acc[et], 0, 0, 0);
        acc[et] = __builtin_amdgcn_mfma_f32_16x16x32_bf16(aL, bH, acc[et], 0, 0, 0);
      }
    }
  }
  atomicAdd(&sZf[strow], zacc);
  __syncthreads();

  const long ub = (long)shd * 4096;
#pragma unroll
  for (int et = 0; et < 4; ++et)
#pragma unroll
    for (int r = 0; r < 4; ++r)
      U[ub + (long)(w * 16 + g * 4 + r) * 64 + et * 16 + ln16] = acc[et][r];
  if (tid < 64) Zs[(long)shd * 64 + tid] = sZf[tid];
}

// ---------------- exclusive prefix over segments ----------------
__global__ __launch_bounds__(256) void seg_prefix(
    const float* __restrict__ U, const float* __restrict__ Zs,
    float* __restrict__ Mem, float* __restrict__ Zp) {
  const int h = blockIdx.x;   // 0..15
  const int jc = blockIdx.y;  // 0..7
  const int tid = threadIdx.x;
  for (int j = jc * 512 + tid; j < jc * 512 + 512; j += 256) {
    float run = 0.f;
#pragma unroll
    for (int t = 0; t < NSEG; ++t) {
      const long idx = ((long)(t * 16 + h)) * 4096 + j;
      Mem[idx] = run;
      run += U[idx];
    }
  }
  if (jc == 0 && tid < 64) {
    float run = 0.f;
#pragma unroll
    for (int t = 0; t < NSEG; ++t) {
      const long idx = ((long)(t * 16 + h)) * 64 + tid;
      Zp[idx] = run;
      run += Zs[idx];
    }
  }
}

// ---------------- MFMA segment attention: 512 thr, 8 waves, 16 q/wave ----------------
// XCD-swizzled blockIdx (T1); V^T staged stride-64 + XOR swizzle (T2), hi-plane only.
__global__ __launch_bounds__(512, 4) void attn_seg_mfma(
    const unsigned* __restrict__ Qp, const unsigned* __restrict__ Kp,
    const unsigned* __restrict__ Vp, const int* __restrict__ mask,
    const float* __restrict__ Mem, const float* __restrict__ Zp,
    const float* __restrict__ betas, unsigned* __restrict__ Op) {
  __shared__ __bf16 sKh[64 * 72], sKl[64 * 72];  // K chunk [key][d]; later Mem^T [e][d]
  __shared__ __bf16 sVTh[64 * 64];               // V^T [e][key], swizzled, hi only
  __shared__ __bf16 sP[8][16 * 72];              // per-wave P (bf16) [q][key]
  __shared__ float sMadd[64], sZ[64], sGate[64];

  // T1: bijective XCD swizzle (nwg = 1024, 1024%8==0): consecutive logical
  // blocks (the 4 qblks of one (seg,h), sharing K/V) land on the same XCD.
  const int bx = (blockIdx.x & 7) * 128 + (blockIdx.x >> 3);
  const int qblk = bx & 3, h = (bx >> 2) & 15, seg = bx >> 6;
  const int sh = seg * 16 + h;
  const int tid = threadIdx.x;
  const int lane = tid & 63, w = tid >> 6;
  const int g = lane >> 4, ln16 = lane & 15;
  const int rsw = (ln16 & 7) << 3;

  // ---- Q fragments (16 queries per wave), packed loads ----
  const int qglob = seg * SEG_S + qblk * 128 + w * 16 + ln16;
  const long qbase = (long)qglob * D_DIM + h * 64;
  bfv8 qh[2], ql[2];
#pragma unroll
  for (int dt = 0; dt < 2; ++dt) {
    u32v4 a = *(const u32v4*)&Qp[qbase + dt * 32 + g * 8];
    u32v4 b = *(const u32v4*)&Qp[qbase + dt * 32 + g * 8 + 4];
    u32v4 hi, lo;
    unpack8(a, b, hi, lo);
    qh[dt] = __builtin_bit_cast(bfv8, hi);
    ql[dt] = __builtin_bit_cast(bfv8, lo);
  }

  fv4 O[4] = {};
  float m_run = -1e30f, l_run = 0.f;
  const long kvbase0 = (long)(seg * SEG_S) * D_DIM + h * 64;

  for (int c = 0; c < 8; ++c) {
    __syncthreads();
    // ---- stage K [64 key][64 d]: 512 thr, 8 els each (conflict-free pattern) ----
    {
      const int row = tid >> 3, d0 = (tid & 7) * 8;
      const long ga = kvbase0 + (long)(c * 64 + row) * D_DIM + d0;
      u32v4 a = *(const u32v4*)&Kp[ga], b = *(const u32v4*)&Kp[ga + 4];
      u32v4 hi, lo;
      unpack8(a, b, hi, lo);
      *(u32v4*)&sKh[row * 72 + d0] = hi;
      *(u32v4*)&sKl[row * 72 + d0] = lo;
    }
    // ---- stage V^T [64 e][64 key], row-per-thread, XOR-swizzled, hi only ----
    {
      const int e = tid & 63, kg = (tid >> 6) * 8;
      u16v8 hv;
#pragma unroll
      for (int j = 0; j < 8; ++j) {
        const unsigned u = Vp[kvbase0 + (long)(c * 64 + kg + j) * D_DIM + e];
        hv[j] = (unsigned short)(u & 0xffffu);
      }
      *(u16v8*)&sVTh[e * 64 + (kg ^ ((e & 7) << 3))] = hv;
    }
    if (tid < 64) sMadd[tid] = (mask[seg * SEG_S + c * 64 + tid] == 0) ? -1e9f : 0.f;
    __syncthreads();

    fv4 madd[4];
#pragma unroll
    for (int kt = 0; kt < 4; ++kt) madd[kt] = *(const fv4*)&sMadd[kt * 16 + g * 4];

    // ---- S^T = K . Q^T (split 3-product) ----
    fv4 sc[4];
#pragma unroll
    for (int kt = 0; kt < 4; ++kt) {
      const int ro = (kt * 16 + ln16) * 72 + g * 8;
      bfv8 kh0 = *(const bfv8*)&sKh[ro], kh1 = *(const bfv8*)&sKh[ro + 32];
      bfv8 kl0 = *(const bfv8*)&sKl[ro], kl1 = *(const bfv8*)&sKl[ro + 32];
      fv4 s = {};
      s = __builtin_amdgcn_mfma_f32_16x16x32_bf16(kh0, qh[0], s, 0, 0, 0);
      s = __builtin_amdgcn_mfma_f32_16x16x32_bf16(kh1, qh[1], s, 0, 0, 0);
      s = __builtin_amdgcn_mfma_f32_16x16x32_bf16(kh0, ql[0], s, 0, 0, 0);
      s = __builtin_amdgcn_mfma_f32_16x16x32_bf16(kh1, ql[1], s, 0, 0, 0);
      s = __builtin_amdgcn_mfma_f32_16x16x32_bf16(kl0, qh[0], s, 0, 0, 0);
      s = __builtin_amdgcn_mfma_f32_16x16x32_bf16(kl1, qh[1], s, 0, 0, 0);
      sc[kt] = s;
    }
    // ---- online softmax (defer-max THR=8) ----
    float pmax = -3.0e38f;
#pragma unroll
    for (int kt = 0; kt < 4; ++kt)
#pragma unroll
      for (int r = 0; r < 4; ++r) {
        const float v = __builtin_fmaf(sc[kt][r], 0.125f, madd[kt][r]);
        sc[kt][r] = v;
        pmax = fmaxf(pmax, v);
      }
    pmax = fmaxf(pmax, __shfl_xor(pmax, 16));
    pmax = fmaxf(pmax, __shfl_xor(pmax, 32));
    if (pmax > m_run + 8.f) {
      const float resc = __expf(m_run - pmax);
      l_run *= resc;
#pragma unroll
      for (int et = 0; et < 4; ++et)
#pragma unroll
        for (int r = 0; r < 4; ++r) O[et][r] *= resc;
      m_run = pmax;
    }
    float psum = 0.f;
#pragma unroll
    for (int kt = 0; kt < 4; ++kt) {
      u16v4 pv;
#pragma unroll
      for (int r = 0; r < 4; ++r) {
        const unsigned short hb = f2bf(__expf(sc[kt][r] - m_run));
        pv[r] = hb;
        psum += bf2f(hb);
      }
      *(u16v4*)&sP[w][ln16 * 72 + kt * 16 + g * 4] = pv;
    }
    psum += __shfl_xor(psum, 16);
    psum += __shfl_xor(psum, 32);
    l_run += psum;

    bfv8 pf0 = *(const bfv8*)&sP[w][ln16 * 72 + g * 8];
    bfv8 pf1 = *(const bfv8*)&sP[w][ln16 * 72 + 32 + g * 8];
    // ---- O^T += V^T . P (V hi only, swizzled reads) ----
#pragma unroll
    for (int et = 0; et < 4; ++et) {
      const int rb = (et * 16 + ln16) * 64;
      bfv8 vh0 = *(const bfv8*)&sVTh[rb + ((g * 8) ^ rsw)];
      bfv8 vh1 = *(const bfv8*)&sVTh[rb + ((g * 8 + 32) ^ rsw)];
      fv4 o = O[et];
      o = __builtin_amdgcn_mfma_f32_16x16x32_bf16(vh0, pf0, o, 0, 0, 0);
      o = __builtin_amdgcn_mfma_f32_16x16x32_bf16(vh1, pf1, o, 0, 0, 0);
      O[et] = o;
    }
  }

  // ---- memory-read term ----
  __syncthreads();
  {  // stage Mem^T [e][d] into sKh/sKl (fp32 source, once per block)
    const int e2 = (tid & 31) * 2, d4 = (tid >> 5) * 4;
    const float* Memp = Mem + (long)sh * 4096;
    fv2 ld[4];
#pragma unroll
    for (int i = 0; i < 4; ++i) ld[i] = *(const fv2*)&Memp[(d4 + i) * 64 + e2];
#pragma unroll
    for (int je = 0; je < 2; ++je) {
      u16v4 hv, lv;
#pragma unroll
      for (int i = 0; i < 4; ++i) {
        const unsigned short hb = f2bf(ld[i][je]);
        hv[i] = hb;
        lv[i] = f2bf(ld[i][je] - bf2f(hb));
      }
      *(u16v4*)&sKh[(e2 + je) * 72 + d4] = hv;
      *(u16v4*)&sKl[(e2 + je) * 72 + d4] = lv;
    }
  }
  if (tid < 64) {
    sZ[tid] = Zp[(long)sh * 64 + tid];
    sGate[tid] = 1.f / (1.f + __expf(-betas[h * 64 + tid]));
  }
  __syncthreads();

  // aq = elu(q)+1 in-register; denom = aq . z
  float dpart = 0.f;
#pragma unroll
  for (int dt = 0; dt < 2; ++dt) {
    u32v4 ah, al;
#pragma unroll
    for (int j = 0; j < 8; ++j) {
      const float x = (float)qh[dt][j] + (float)ql[dt][j];
      const float a = x > 0.f ? x + 1.f : __expf(x);
      dpart += a * sZ[dt * 32 + g * 8 + j];
      const unsigned short hb = f2bf(a);
      ((unsigned short*)&ah)[j] = hb;
      ((unsigned short*)&al)[j] = f2bf(a - bf2f(hb));
    }
    qh[dt] = __builtin_bit_cast(bfv8, ah);
    ql[dt] = __builtin_bit_cast(bfv8, al);
  }
  dpart += __shfl_xor(dpart, 16);
  dpart += __shfl_xor(dpart, 32);
  const float invden = 1.f / (dpart + 1e-9f);
  const float invl = 1.f / l_run;

  const long obase = (long)qglob * D_DIM + h * 64;
#pragma unroll
  for (int et = 0; et < 4; ++et) {
    const int ro = (et * 16 + ln16) * 72 + g * 8;
    bfv8 mh0 = *(const bfv8*)&sKh[ro], mh1 = *(const bfv8*)&sKh[ro + 32];
    bfv8 ml0 = *(const bfv8*)&sKl[ro], ml1 = *(const bfv8*)&sKl[ro + 32];
    fv4 o = {};
    o = __builtin_amdgcn_mfma_f32_16x16x32_bf16(mh0, qh[0], o, 0, 0, 0);
    o = __builtin_amdgcn_mfma_f32_16x16x32_bf16(mh1, qh[1], o, 0, 0, 0);
    o = __builtin_amdgcn_mfma_f32_16x16x32_bf16(mh0, ql[0], o, 0, 0, 0);
    o = __builtin_amdgcn_mfma_f32_16x16x32_bf16(mh1, ql[1], o, 0, 0, 0);
    o = __builtin_amdgcn_mfma_f32_16x16x32_bf16(ml0, qh[0], o, 0, 0, 0);
    o = __builtin_amdgcn_mfma_f32_16x16x32_bf16(ml1, qh[1], o, 0, 0, 0);
    const fv4 gt = *(const fv4*)&sGate[et * 16 + g * 4];
    u32v4 st;
#pragma unroll
    for (int r = 0; r < 4; ++r) {
      const float att = gt[r] * o[r] * invden + (1.f - gt[r]) * O[et][r] * invl;
      st[r] = packbf2(att);
    }
    *(u32v4*)&Op[obase + et * 16 + g * 4] = st;
  }
}

// ---------------- host launch: batch-tiled to bound workspace ----------------
extern "C" void kernel_launch(void* const* d_in, const int* in_sizes, int n_in,
                              void* d_out, int out_size, void* d_ws, size_t ws_size,
                              hipStream_t stream) {
  (void)in_sizes; (void)n_in; (void)out_size;
  const float* x     = (const float*)d_in[0];
  const int*   mask  = (const int*)d_in[1];
  const float* wq    = (const float*)d_in[2];
  const float* wk    = (const float*)d_in[3];
  const float* wv    = (const float*)d_in[4];
  const float* wo    = (const float*)d_in[5];
  const float* wob   = (const float*)d_in[6];
  const float* betas = (const float*)d_in[7];
  float* out = (float*)d_out;

  const size_t TOKB = (size_t)MB_TOK * D_DIM;
  char* ws = (char*)d_ws;
  size_t off = 0;
  auto alloc = [&](size_t bytes) {
    char* p = ws + off;
    off += (bytes + 255) & ~(size_t)255;
    return p;
  };
  unsigned* wsp[4];
  for (int i = 0; i < 4; ++i)
    wsp[i] = (unsigned*)alloc((size_t)D_DIM * D_DIM * 4);
  unsigned* xp = (unsigned*)alloc(TOKB * 4);
  unsigned* qp = (unsigned*)alloc(TOKB * 4);
  unsigned* kp = (unsigned*)alloc(TOKB * 4);
  unsigned* vp = (unsigned*)alloc(TOKB * 4);
  float* U   = (float*)alloc((size_t)NSEG * H_NUM * 4096 * 4);
  float* Mem = (float*)alloc((size_t)NSEG * H_NUM * 4096 * 4);
  float* Zs  = (float*)alloc((size_t)NSEG * H_NUM * 64 * 4);
  float* Zp  = (float*)alloc((size_t)NSEG * H_NUM * 64 * 4);
  unsigned* attp = xp;  // x dead after QKV GEMMs

  if (off > ws_size) return;

  const float* wsrc[4] = {wq, wk, wv, wo};
  for (int i = 0; i < 4; ++i)
    split_pack<<<1024, 256, 0, stream>>>(wsrc[i], wsp[i], D_DIM * D_DIM / 4);

  dim3 ggrid(D_DIM / 128, MB_TOK / 128);
  dim3 pgrid(H_NUM, 8);
  for (int b = 0; b < B_DIM; ++b) {
    const float* xb = x + (size_t)b * TOKB;
    const int* maskb = mask + (size_t)b * L_DIM;
    float* outb = out + (size_t)b * TOKB;

    split_pack<<<2048, 256, 0, stream>>>(xb, xp, (int)(TOKB / 4));

    gemm_bt_packed<<<ggrid, 256, 0, stream>>>(xp, wsp[0], nullptr, nullptr, qp,
                                              MB_TOK, D_DIM, D_DIM);
    gemm_bt_packed<<<ggrid, 256, 0, stream>>>(xp, wsp[1], nullptr, nullptr, kp,
                                              MB_TOK, D_DIM, D_DIM);
    gemm_bt_packed<<<ggrid, 256, 0, stream>>>(xp, wsp[2], nullptr, nullptr, vp,
                                              MB_TOK, D_DIM, D_DIM);

    seg_outer_mfma<<<NSEG * H_NUM, 256, 0, stream>>>(kp, vp, U, Zs);
    seg_prefix<<<pgrid, 256, 0, stream>>>(U, Zs, Mem, Zp);

    attn_seg_mfma<<<NSEG * H_NUM * 4, 512, 0, stream>>>(qp, kp, vp, maskb, Mem, Zp,
                                                        betas, attp);

    gemm_bt_packed<<<ggrid, 256, 0, stream>>>(attp, wsp[3], outb, wob, nullptr,
                                              MB_TOK, D_DIM, D_DIM);
  }
}